// Round 10
// baseline (562.082 us; speedup 1.0000x reference)
//
#include <hip/hip_runtime.h>

#define N_NODES 50000
#define N_EDGES 800000
#define HDIM 128
#define N_GRAPH 2048

typedef __bf16 bf16x8 __attribute__((ext_vector_type(8)));
typedef float f32x4 __attribute__((ext_vector_type(4)));
typedef float f32x16 __attribute__((ext_vector_type(16)));

// round-to-nearest-even fp32 -> bf16
static __device__ __forceinline__ unsigned short f2bf(float f) {
    unsigned int u = __float_as_uint(f);
    u += 0x7fffu + ((u >> 16) & 1u);
    return (unsigned short)(u >> 16);
}
static __device__ __forceinline__ float bflo(unsigned int u) { return __uint_as_float(u << 16); }
static __device__ __forceinline__ float bfhi(unsigned int u) { return __uint_as_float(u & 0xFFFF0000u); }

// one-instruction RNE pair conversion (same rounding as f2bf), replaces ~9 inst
static __device__ __forceinline__ unsigned int cvt_pk_bf16(float lo, float hi) {
    unsigned int r;
    asm("v_cvt_pk_bf16_f32 %0, %1, %2" : "=v"(r) : "v"(lo), "v"(hi));
    return r;
}

// fast silu: x * rcp(1 + 2^(-x*log2e)) -> v_exp_f32 + v_rcp_f32, ~5 inst
static __device__ __forceinline__ float silu_f(float x) {
    float e = __builtin_amdgcn_exp2f(x * -1.44269504f);
    return x * __builtin_amdgcn_rcpf(1.0f + e);
}

// ---- fused one-shot prep (blocks < 1408) + src histogram + agg zero ----
#define PREP_BLOCKS 1408
#define HIST_BLOCKS 3125
#define ZERO_BLOCKS 6250   // N*HDIM*4B / (256*16B) = 6250 exact
__global__ void prep_hist_kernel(const float* __restrict__ ew1, const float* __restrict__ ew2,
                                 const float* __restrict__ nw1, const float* __restrict__ nw2,
                                 const float* __restrict__ eb1, const float* __restrict__ lattices,
                                 const int* __restrict__ eidx,
                                 unsigned short* __restrict__ W1aT, unsigned short* __restrict__ W1bT,
                                 unsigned short* __restrict__ W2t, unsigned short* __restrict__ N1t,
                                 unsigned short* __restrict__ N2t, unsigned short* __restrict__ Lb,
                                 int* __restrict__ buf, float* __restrict__ agg) {
    const int bid = blockIdx.x;
    if (bid >= PREP_BLOCKS + HIST_BLOCKS) {
        // zero agg (= d_out) so edge_kernel atomics start from 0
        const int idx = (bid - PREP_BLOCKS - HIST_BLOCKS) * 256 + threadIdx.x;
        ((float4*)agg)[idx] = make_float4(0.f, 0.f, 0.f, 0.f);
        return;
    }
    if (bid >= PREP_BLOCKS) {
        int e = (bid - PREP_BLOCKS) * 256 + threadIdx.x;
        if (e < N_EDGES) atomicAdd(&buf[eidx[e]], 1);
        return;
    }
    int i = bid * 256 + threadIdx.x;
    if (i < 16384) {
        int n = i >> 7, k = i & 127;
        W1aT[i] = f2bf(ew1[k * 128 + n]);
    } else if (i < 32768) {
        int j = i - 16384; int n = j >> 7, k = j & 127;
        W1bT[j] = f2bf(ew1[(128 + k) * 128 + n]);
    } else if (i < 49152) {
        int j = i - 32768; int n = j >> 7, k = j & 127;
        W2t[j] = f2bf(ew2[k * 128 + n]);
    } else if (i < 81920) {
        int j = i - 49152; int n = j >> 8, k = j & 255;
        N1t[j] = f2bf(nw1[k * 128 + n]);
    } else if (i < 98304) {
        int j = i - 81920; int n = j >> 7, k = j & 127;
        N2t[j] = f2bf(nw2[k * 128 + n]);
    } else if (i < 98304 + 262144) {
        int j = i - 98304; int g = j >> 7, c = j & 127;
        float s = eb1[c];
#pragma unroll
        for (int t = 0; t < 6; ++t) s += lattices[g * 6 + t] * ew1[(256 + t) * 128 + c];
        Lb[j] = f2bf(s);
    }
}

// single-block scan; wave-shuffle scan at 1024 threads (best measured: R7
// non-edge 296us; the 256-thread fused variant regressed +27us in R8).
__global__ __launch_bounds__(1024) void scan_kernel(int* __restrict__ buf) {
    constexpr int CH = 12288;
    __shared__ int lds[CH];
    __shared__ int wpart[16];
    __shared__ int carry_s;
    const int t = threadIdx.x;
    const int wave = t >> 6, lane = t & 63;
    if (t == 0) carry_s = 0;
    __syncthreads();
#pragma unroll 1
    for (int base = 0; base < N_NODES; base += CH) {
#pragma unroll
        for (int k = 0; k < CH / 1024; ++k) {
            int f = k * 1024 + t;
            lds[f] = (base + f < N_NODES) ? buf[base + f] : 0;
        }
        __syncthreads();
        int loc[12];
        int s = 0;
#pragma unroll
        for (int i = 0; i < 12; ++i) { loc[i] = lds[t * 12 + i]; s += loc[i]; }
        // wave-level inclusive scan of s (no barriers)
        int ps = s;
#pragma unroll
        for (int off = 1; off < 64; off <<= 1) {
            int v = __shfl_up(ps, off);
            if (lane >= off) ps += v;
        }
        if (lane == 63) wpart[wave] = ps;   // wave total
        __syncthreads();
        if (t == 0) {
            int r = carry_s;
#pragma unroll
            for (int i = 0; i < 16; ++i) { int v = wpart[i]; wpart[i] = r; r += v; }
            carry_s = r;                     // new carry = old + chunk total
        }
        __syncthreads();
        int run = wpart[wave] + (ps - s);    // exclusive prefix for this thread
#pragma unroll
        for (int i = 0; i < 12; ++i) { int tmp = loc[i]; lds[t * 12 + i] = run; run += tmp; }
        __syncthreads();
#pragma unroll
        for (int k = 0; k < CH / 1024; ++k) {
            int f = k * 1024 + t;
            if (base + f < N_NODES) buf[base + f] = lds[f];
        }
        __syncthreads();
    }
}

// ---- fused perm scatter (blocks < 3125) + pq precompute (blocks >= 3125) ----
#define PERM_BLOCKS2 3125
#define PQ_BLOCKS ((N_NODES + 63) / 64)
__global__ __launch_bounds__(256, 4) void perm_pq_kernel(
    const int* __restrict__ eidx, const int* __restrict__ e2g,
    const float* __restrict__ frac_diff, int* __restrict__ buf,
    unsigned short* __restrict__ perm_lo, unsigned char* __restrict__ perm_hi,
    uint4* __restrict__ rec, const int packed,
    const float* __restrict__ nf, const unsigned short* __restrict__ W1aT,
    const unsigned short* __restrict__ W1bT,
    unsigned short* __restrict__ P, unsigned short* __restrict__ Qm) {
    constexpr int SA = 136;
    __shared__ unsigned short sm[64 * SA];
    const int bid = blockIdx.x;
    const int tid = threadIdx.x;

    if (bid < PERM_BLOCKS2) {
        int e = bid * 256 + tid;
        if (e < N_EDGES) {
            int s = eidx[e];
            int pos = atomicAdd(&buf[s], 1);
            if (packed) {
                int d = eidx[N_EDGES + e];
                int g = e2g[e];
                unsigned int w0 = (unsigned int)s | ((unsigned int)d << 16);
                unsigned int w1 = (unsigned int)g | ((unsigned int)f2bf(frac_diff[3 * e]) << 16);
                unsigned int w2 = (unsigned int)f2bf(frac_diff[3 * e + 1]) |
                                  ((unsigned int)f2bf(frac_diff[3 * e + 2]) << 16);
                rec[pos] = make_uint4(w0, w1, w2, 0u);
            } else {
                perm_lo[pos] = (unsigned short)(e & 0xFFFF);
                perm_hi[pos] = (unsigned char)(e >> 16);
            }
        }
        return;
    }

    const int n0 = (bid - PERM_BLOCKS2) * 64;
    const int mrow = tid >> 2, q = tid & 3;
    {
        const int node = n0 + mrow;
        unsigned short* row = sm + mrow * SA + q * 32;
        if (node < N_NODES) {
            const float4* a4 = (const float4*)(nf + (size_t)node * HDIM) + q * 8;
#pragma unroll
            for (int j = 0; j < 8; ++j) {
                float4 v = a4[j];
                *(ushort4*)(row + 4 * j) = make_ushort4(f2bf(v.x), f2bf(v.y), f2bf(v.z), f2bf(v.w));
            }
        } else {
#pragma unroll
            for (int j = 0; j < 8; ++j) *(ushort4*)(row + 4 * j) = make_ushort4(0, 0, 0, 0);
        }
    }
    __syncthreads();

    const int wave = tid >> 6, lane = tid & 63;
    const int lr = lane & 15, kq = lane >> 4;
    f32x4 acca[8] = {}, accb[8] = {};
    const int arow = (wave * 16 + lr) * SA;
#pragma unroll
    for (int ks = 0; ks < 128; ks += 32) {
        bf16x8 a = *(const bf16x8*)(sm + arow + ks + kq * 8);
#pragma unroll
        for (int nt = 0; nt < 8; ++nt) {
            bf16x8 ba = *(const bf16x8*)(W1aT + (nt * 16 + lr) * 128 + ks + kq * 8);
            acca[nt] = __builtin_amdgcn_mfma_f32_16x16x32_bf16(a, ba, acca[nt], 0, 0, 0);
            bf16x8 bb = *(const bf16x8*)(W1bT + (nt * 16 + lr) * 128 + ks + kq * 8);
            accb[nt] = __builtin_amdgcn_mfma_f32_16x16x32_bf16(a, bb, accb[nt], 0, 0, 0);
        }
    }
    __syncthreads();

    const int node = n0 + mrow;
#pragma unroll
    for (int nt = 0; nt < 8; ++nt) {
        const int col = nt * 16 + lr;
#pragma unroll
        for (int r = 0; r < 4; ++r)
            sm[(wave * 16 + kq * 4 + r) * SA + col] = f2bf(acca[nt][r]);
    }
    __syncthreads();
    if (node < N_NODES) {
        uint4* dst = (uint4*)(P + (size_t)node * HDIM + q * 32);
        const uint4* srcp = (const uint4*)(sm + mrow * SA + q * 32);
#pragma unroll
        for (int j = 0; j < 4; ++j) dst[j] = srcp[j];
    }
    __syncthreads();
#pragma unroll
    for (int nt = 0; nt < 8; ++nt) {
        const int col = nt * 16 + lr;
#pragma unroll
        for (int r = 0; r < 4; ++r)
            sm[(wave * 16 + kq * 4 + r) * SA + col] = f2bf(accb[nt][r]);
    }
    __syncthreads();
    if (node < N_NODES) {
        uint4* dst = (uint4*)(Qm + (size_t)node * HDIM + q * 32);
        const uint4* srcp = (const uint4*)(sm + mrow * SA + q * 32);
#pragma unroll
        for (int j = 0; j < 4; ++j) dst[j] = srcp[j];
    }
}

// ================= edge kernel helpers (32x32 MFMA path) =================

// build A-fragments from gathered P/Q/Lb rows + fd * (bf16 weights from LDS)
static __device__ __forceinline__ void build_afrag(
    const uint4* pu, const uint4* qu, const uint4* lu,
    float f0, float f1, float f2,
    const unsigned int* wlds, int hi, bf16x8* afrag) {
#pragma unroll
    for (int kk = 0; kk < 8; ++kk) {
        const unsigned int* wl = wlds + (kk * 2 + hi) * 12;
        const uint4 w0v = *(const uint4*)(wl);
        const uint4 w1v = *(const uint4*)(wl + 4);
        const uint4 w2v = *(const uint4*)(wl + 8);
        const unsigned int* pw = (const unsigned int*)&pu[kk];
        const unsigned int* qw = (const unsigned int*)&qu[kk];
        const unsigned int* lw = (const unsigned int*)&lu[kk];
        const unsigned int* w0w = (const unsigned int*)&w0v;
        const unsigned int* w1w = (const unsigned int*)&w1v;
        const unsigned int* w2w = (const unsigned int*)&w2v;
        unsigned int ow[4];
#pragma unroll
        for (int w = 0; w < 4; ++w) {
            float x0 = bflo(pw[w]) + bflo(qw[w]) + bflo(lw[w])
                     + f0 * bflo(w0w[w]) + f1 * bflo(w1w[w]) + f2 * bflo(w2w[w]);
            float x1 = bfhi(pw[w]) + bfhi(qw[w]) + bfhi(lw[w])
                     + f0 * bfhi(w0w[w]) + f1 * bfhi(w1w[w]) + f2 * bfhi(w2w[w]);
            ow[w] = cvt_pk_bf16(silu_f(x0), silu_f(x1));
        }
        afrag[kk] = *(bf16x8*)ow;
    }
}

// NOTE: no s_setprio here — R7 measured it pins the schedule and causes a
// mild scratch spill (+43MB TCC traffic, +25us). Plain cluster is fastest.
static __device__ __forceinline__ void do_mfma(
    const bf16x8* afrag, const unsigned short* __restrict__ W2t,
    int row, int hi, f32x16* acc) {
#pragma unroll
    for (int kk = 0; kk < 8; ++kk) {
#pragma unroll
        for (int t4 = 0; t4 < 4; ++t4) {
            bf16x8 bb = *(const bf16x8*)(W2t + (t4 * 32 + row) * 128 + kk * 16 + hi * 8);
            acc[t4] = __builtin_amdgcn_mfma_f32_32x32x16_bf16(afrag[kk], bb, acc[t4], 0, 0, 0);
        }
    }
}

// segmented reduction over 32 sorted rows on the 32x32 C layout
// (row = (reg&3) + 8*(reg>>2) + 4*hi); hi-halves merged via shfl_xor.
// seg[a,b] emitted as +prefix[b] to src[b], -prefix[a-1] to src[a]
static __device__ __forceinline__ void epilogue(
    const f32x16* acc, const int* sc, const int* snq,
    int row, int hi, const float* __restrict__ b2, float* __restrict__ agg) {
#pragma unroll
    for (int t4 = 0; t4 < 4; ++t4) {
        const int col = t4 * 32 + row;
        const float bias = b2[col];
        float p[16], tq[4], to[4];
#pragma unroll
        for (int rq = 0; rq < 4; ++rq) {
            float s0 = silu_f(acc[t4][4 * rq + 0] + bias);
            float s1 = silu_f(acc[t4][4 * rq + 1] + bias);
            float s2 = silu_f(acc[t4][4 * rq + 2] + bias);
            float s3 = silu_f(acc[t4][4 * rq + 3] + bias);
            p[4 * rq + 0] = s0;
            p[4 * rq + 1] = s0 + s1;
            p[4 * rq + 2] = p[4 * rq + 1] + s2;
            p[4 * rq + 3] = p[4 * rq + 2] + s3;
            tq[rq] = p[4 * rq + 3];
            to[rq] = __shfl_xor(tq[rq], 32);
        }
        float cum = 0.f;
#pragma unroll
        for (int rq = 0; rq < 4; ++rq) {
            const float off = cum + (hi ? to[rq] : 0.f);
            cum += tq[rq] + to[rq];
#pragma unroll
            for (int i = 0; i < 4; ++i) {
                const int r = 4 * rq + i;
                const float val = p[r] + off;
                const int myrow = 4 * (2 * rq + hi) + i;
                const bool lastg = (myrow == 31);
                const int nxt = (i < 3) ? sc[r + 1] : snq[rq];
                const bool bnd = lastg || (sc[r] != nxt);
                if (bnd) {
                    atomicAdd(&agg[(size_t)sc[r] * HDIM + col], val);
                    if (!lastg) atomicAdd(&agg[(size_t)nxt * HDIM + col], -val);
                }
            }
        }
    }
}

// ---- edge kernel: 64 edges/wave = two straight-line 32-edge chunks (best
// measured: 211-215us at 2 waves/SIMD). This round's single change:
// __launch_bounds__(256,3) caps total regs at 170 (arch <=106 + 64 AGPR) to
// reach 3 waves/SIMD. The allocator must sink chunk-B gather issue later —
// trading in-wave prefetch depth for 1.5x TLP. Verification: WRITE_SIZE
// stays ~61.7MB (no spill) and occupancy rises to ~30%.
#define EDGE_NWG (N_EDGES / 256)   // 3125 blocks of 4 waves x 64 edges
template <bool PACKED>
static __device__ __forceinline__ void fetch_meta(
    int i, const uint4* __restrict__ rec, const int* __restrict__ eidx,
    const int* __restrict__ e2g, const float* __restrict__ frac_diff,
    const unsigned short* __restrict__ perm_lo, const unsigned char* __restrict__ perm_hi,
    int& src, int& dst, int& g, float& f0, float& f1, float& f2) {
    if (PACKED) {
        const uint4 rv = rec[i];
        src = rv.x & 0xFFFF;
        dst = rv.x >> 16;
        g = rv.y & 0xFFFF;
        f0 = bfhi(rv.y);
        f1 = bflo(rv.z);
        f2 = bfhi(rv.z);
    } else {
        const int e = (int)perm_lo[i] | ((int)perm_hi[i] << 16);
        src = eidx[e];
        dst = eidx[N_EDGES + e];
        g = e2g[e];
        f0 = frac_diff[3 * e];
        f1 = frac_diff[3 * e + 1];
        f2 = frac_diff[3 * e + 2];
    }
}

static __device__ __forceinline__ void gather_rows(
    const unsigned short* __restrict__ P, const unsigned short* __restrict__ Qm,
    const unsigned short* __restrict__ Lb,
    int src, int dst, int g, int hi, uint4* pu, uint4* qu, uint4* lu) {
    const size_t pr = (size_t)src * HDIM, qr = (size_t)dst * HDIM, lr = (size_t)g * HDIM;
#pragma unroll
    for (int kk = 0; kk < 8; ++kk) {
        const int c0 = kk * 16 + hi * 8;
        pu[kk] = *(const uint4*)(P + pr + c0);
        qu[kk] = *(const uint4*)(Qm + qr + c0);
        lu[kk] = *(const uint4*)(Lb + lr + c0);
    }
}

static __device__ __forceinline__ void make_sc(int src, int hi, int* sc, int* snq) {
#pragma unroll
    for (int r = 0; r < 16; ++r) sc[r] = __shfl(src, (r & 3) + 8 * (r >> 2) + 4 * hi);
#pragma unroll
    for (int j = 0; j < 4; ++j) snq[j] = __shfl(src, (4 * (2 * j + hi) + 4) & 31);
}

template <bool PACKED>
__global__ __launch_bounds__(256, 3) void edge_kernel(
    const unsigned short* __restrict__ P, const unsigned short* __restrict__ Qm,
    const unsigned short* __restrict__ Lb, const float* __restrict__ frac_diff,
    const int* __restrict__ eidx, const int* __restrict__ e2g,
    const unsigned short* __restrict__ perm_lo, const unsigned char* __restrict__ perm_hi,
    const uint4* __restrict__ rec,
    const float* __restrict__ e_w1, const unsigned short* __restrict__ W2t,
    const float* __restrict__ b2, float* __restrict__ agg) {
    // fd-weight columns of e_w1 (rows 262..264) as bf16 pairs in LDS:
    // layout [kk][hi][rw][4 dwords]; reads are 2-address broadcasts (free).
    __shared__ __align__(16) unsigned int wlds[192];
    const int tid = threadIdx.x;
    {
        const float* wrbase = e_w1 + 262 * HDIM;
        if (tid < 192) {
            const int w = tid & 3, rw = (tid >> 2) % 3, hi = (tid / 12) & 1, kk = tid / 24;
            const int c = kk * 16 + hi * 8 + 2 * w;
            wlds[((kk * 2 + hi) * 3 + rw) * 4 + w] =
                (unsigned int)f2bf(wrbase[rw * HDIM + c]) |
                ((unsigned int)f2bf(wrbase[rw * HDIM + c + 1]) << 16);
        }
    }
    __syncthreads();

    const int wv = tid >> 6, lane = tid & 63;
    const int row = lane & 31, hi = lane >> 5;
    const int base = (blockIdx.x * 4 + wv) * 64;   // this wave's 64 edges

    // ---- metadata for both chunks ----
    int srcA, dstA, gA; float fA0, fA1, fA2;
    fetch_meta<PACKED>(base + row, rec, eidx, e2g, frac_diff, perm_lo, perm_hi,
                       srcA, dstA, gA, fA0, fA1, fA2);
    int srcB, dstB, gB; float fB0, fB1, fB2;
    fetch_meta<PACKED>(base + 32 + row, rec, eidx, e2g, frac_diff, perm_lo, perm_hi,
                       srcB, dstB, gB, fB0, fB1, fB2);

    // ---- chunk A+B gathers up-front (B's latency hides under A compute;
    // under the 3-wave cap the scheduler may sink part of B's issue) ----
    uint4 puA[8], quA[8], luA[8];
    gather_rows(P, Qm, Lb, srcA, dstA, gA, hi, puA, quA, luA);
    uint4 puB[8], quB[8], luB[8];
    gather_rows(P, Qm, Lb, srcB, dstB, gB, hi, puB, quB, luB);

    // ---- chunk A: afrag -> MFMA -> epilogue ----
    {
        bf16x8 afrag[8];
        build_afrag(puA, quA, luA, fA0, fA1, fA2, wlds, hi, afrag);
        int sc[16], snq[4];
        make_sc(srcA, hi, sc, snq);
        f32x16 acc[4] = {};
        do_mfma(afrag, W2t, row, hi, acc);
        epilogue(acc, sc, snq, row, hi, b2, agg);
    }

    // ---- chunk B: afrag -> MFMA -> epilogue ----
    {
        bf16x8 afrag[8];
        build_afrag(puB, quB, luB, fB0, fB1, fB2, wlds, hi, afrag);
        int sc[16], snq[4];
        make_sc(srcB, hi, sc, snq);
        f32x16 acc[4] = {};
        do_mfma(afrag, W2t, row, hi, acc);
        epilogue(acc, sc, snq, row, hi, b2, agg);
    }
}

// ---- node MLP: h = concat(nf, agg/cnt) -> silu -> silu -> + nf (agg aliases out) ----
__global__ __launch_bounds__(256, 4) void node_kernel(
    const float* __restrict__ nf, const float* __restrict__ agg,
    const int* __restrict__ buf,
    const unsigned short* __restrict__ N1t, const float* __restrict__ b1,
    const unsigned short* __restrict__ N2t, const float* __restrict__ b2,
    float* __restrict__ out) {
    constexpr int SA = 264;
    constexpr int S2 = 136;
    constexpr int SFo = 132;
    __shared__ unsigned short sm[64 * SA];
    float* smf = (float*)sm;

    const int tid = threadIdx.x;
    const int n0 = blockIdx.x * 64;
    const int mrow = tid >> 2, q = tid & 3;
    {
        const int node = n0 + mrow;
        unsigned short* row = sm + mrow * SA;
        const int cbq = q * 32;
        if (node < N_NODES) {
            const int c = buf[node] - (node ? buf[node - 1] : 0);
            const float inv = 1.0f / (float)max(c, 1);
            const float4* a4 = (const float4*)(nf + (size_t)node * HDIM) + q * 8;
            const float4* g4 = (const float4*)(agg + (size_t)node * HDIM) + q * 8;
#pragma unroll
            for (int j = 0; j < 8; ++j) {
                float4 v = a4[j];
                *(ushort4*)(row + cbq + 4 * j) =
                    make_ushort4(f2bf(v.x), f2bf(v.y), f2bf(v.z), f2bf(v.w));
                float4 g = g4[j];
                *(ushort4*)(row + HDIM + cbq + 4 * j) =
                    make_ushort4(f2bf(g.x * inv), f2bf(g.y * inv), f2bf(g.z * inv), f2bf(g.w * inv));
            }
        } else {
#pragma unroll
            for (int j = 0; j < 8; ++j) {
                *(ushort4*)(row + cbq + 4 * j) = make_ushort4(0, 0, 0, 0);
                *(ushort4*)(row + HDIM + cbq + 4 * j) = make_ushort4(0, 0, 0, 0);
            }
        }
    }
    __syncthreads();

    const int wave = tid >> 6, lane = tid & 63;
    const int lr = lane & 15, kq = lane >> 4;

    f32x4 acc[8] = {};
    const int arow = (wave * 16 + lr) * SA;
#pragma unroll
    for (int ks = 0; ks < 256; ks += 32) {
        bf16x8 a = *(const bf16x8*)(sm + arow + ks + kq * 8);
#pragma unroll
        for (int nt = 0; nt < 8; ++nt) {
            bf16x8 bb = *(const bf16x8*)(N1t + (nt * 16 + lr) * 256 + ks + kq * 8);
            acc[nt] = __builtin_amdgcn_mfma_f32_16x16x32_bf16(a, bb, acc[nt], 0, 0, 0);
        }
    }
    __syncthreads();

#pragma unroll
    for (int nt = 0; nt < 8; ++nt) {
        const int col = nt * 16 + lr;
        const float bias = b1[col];
#pragma unroll
        for (int r = 0; r < 4; ++r) {
            const int mm = wave * 16 + kq * 4 + r;
            sm[mm * S2 + col] = f2bf(silu_f(acc[nt][r] + bias));
        }
    }
    __syncthreads();

    f32x4 acc2[8] = {};
    const int arow2 = (wave * 16 + lr) * S2;
#pragma unroll
    for (int ks = 0; ks < 128; ks += 32) {
        bf16x8 a = *(const bf16x8*)(sm + arow2 + ks + kq * 8);
#pragma unroll
        for (int nt = 0; nt < 8; ++nt) {
            bf16x8 bb = *(const bf16x8*)(N2t + (nt * 16 + lr) * 128 + ks + kq * 8);
            acc2[nt] = __builtin_amdgcn_mfma_f32_16x16x32_bf16(a, bb, acc2[nt], 0, 0, 0);
        }
    }
    __syncthreads();

#pragma unroll
    for (int nt = 0; nt < 8; ++nt) {
        const int col = nt * 16 + lr;
        const float bias = b2[col];
#pragma unroll
        for (int r = 0; r < 4; ++r) {
            const int mm = wave * 16 + kq * 4 + r;
            smf[mm * SFo + col] = silu_f(acc2[nt][r] + bias);
        }
    }
    __syncthreads();
    {
        const int node = n0 + mrow;
        if (node < N_NODES) {
            const float4* nfr = (const float4*)(nf + (size_t)node * HDIM) + q * 8;
            float4* outr = (float4*)(out + (size_t)node * HDIM) + q * 8;
            const float* st = smf + mrow * SFo + q * 32;
#pragma unroll
            for (int j = 0; j < 8; ++j) {
                float4 v = nfr[j];
                float4 s4 = *(const float4*)(st + 4 * j);
                v.x += s4.x; v.y += s4.y; v.z += s4.z; v.w += s4.w;
                outr[j] = v;
            }
        }
    }
}

extern "C" void kernel_launch(void* const* d_in, const int* in_sizes, int n_in,
                              void* d_out, int out_size, void* d_ws, size_t ws_size,
                              hipStream_t stream) {
    const float* node_features = (const float*)d_in[0];
    const float* lattices = (const float*)d_in[2];
    const float* frac_diff = (const float*)d_in[3];
    const int* edge_index = (const int*)d_in[4];
    const int* edge2graph = (const int*)d_in[5];
    const float* e_w1 = (const float*)d_in[6];
    const float* e_b1 = (const float*)d_in[7];
    const float* e_w2 = (const float*)d_in[8];
    const float* e_b2 = (const float*)d_in[9];
    const float* n_w1 = (const float*)d_in[10];
    const float* n_b1 = (const float*)d_in[11];
    const float* n_w2 = (const float*)d_in[12];
    const float* n_b2 = (const float*)d_in[13];

    // workspace layout (bytes):
    //   0         W1aT | 32768 W1bT | 65536 W2t | 98304 N1t | 163840 N2t
    //   196608    Lb   (G*128 bf16)
    //   720896    P    (N*128 bf16, 12.8MB)
    //   13520896  Q    (N*128 bf16, 12.8MB)
    //   26320896  buf  (N int)
    //   26520896  perm_lo (E u16) | 28120896 perm_hi (E u8)   [fallback path]
    //   28920896  rec  (E x 16B packed sorted metadata)       [packed path, if ws fits]
    // agg lives in d_out (node_kernel reads its own rows before overwriting).
    char* ws = (char*)d_ws;
    unsigned short* W1aT = (unsigned short*)(ws);
    unsigned short* W1bT = (unsigned short*)(ws + 32768);
    unsigned short* W2t  = (unsigned short*)(ws + 65536);
    unsigned short* N1t  = (unsigned short*)(ws + 98304);
    unsigned short* N2t  = (unsigned short*)(ws + 163840);
    unsigned short* Lb   = (unsigned short*)(ws + 196608);
    unsigned short* P    = (unsigned short*)(ws + 720896);
    unsigned short* Qm   = (unsigned short*)(ws + 13520896);
    int* buf             = (int*)(ws + 26320896);
    unsigned short* perm_lo = (unsigned short*)(ws + 26520896);
    unsigned char* perm_hi  = (unsigned char*)(ws + 28120896);
    uint4* rec           = (uint4*)(ws + 28920896);
    float* agg = (float*)d_out;

    // ws_size is fixed for the session -> this branch is deterministic (graph-safe)
    const int packed = (ws_size >= 28920896 + (size_t)N_EDGES * 16) ? 1 : 0;

    hipMemsetAsync(buf, 0, (size_t)N_NODES * 4, stream);

    prep_hist_kernel<<<PREP_BLOCKS + HIST_BLOCKS + ZERO_BLOCKS, 256, 0, stream>>>(
        e_w1, e_w2, n_w1, n_w2, e_b1, lattices, edge_index,
        W1aT, W1bT, W2t, N1t, N2t, Lb, buf, agg);

    scan_kernel<<<1, 1024, 0, stream>>>(buf);

    perm_pq_kernel<<<PERM_BLOCKS2 + PQ_BLOCKS, 256, 0, stream>>>(
        edge_index, edge2graph, frac_diff, buf, perm_lo, perm_hi, rec, packed,
        node_features, W1aT, W1bT, P, Qm);

    if (packed) {
        edge_kernel<true><<<EDGE_NWG, 256, 0, stream>>>(
            P, Qm, Lb, frac_diff, edge_index, edge2graph, perm_lo, perm_hi, rec,
            e_w1, W2t, e_b2, agg);
    } else {
        edge_kernel<false><<<EDGE_NWG, 256, 0, stream>>>(
            P, Qm, Lb, frac_diff, edge_index, edge2graph, perm_lo, perm_hi, rec,
            e_w1, W2t, e_b2, agg);
    }

    node_kernel<<<(N_NODES + 63) / 64, 256, 0, stream>>>(
        node_features, agg, buf, N1t, n_b1, N2t, n_b2, (float*)d_out);
}

// Round 11
// 506.406 us; speedup vs baseline: 1.1099x; 1.1099x over previous
//
#include <hip/hip_runtime.h>

#define N_NODES 50000
#define N_EDGES 800000
#define HDIM 128
#define N_GRAPH 2048

typedef __bf16 bf16x8 __attribute__((ext_vector_type(8)));
typedef float f32x4 __attribute__((ext_vector_type(4)));
typedef float f32x16 __attribute__((ext_vector_type(16)));

// round-to-nearest-even fp32 -> bf16
static __device__ __forceinline__ unsigned short f2bf(float f) {
    unsigned int u = __float_as_uint(f);
    u += 0x7fffu + ((u >> 16) & 1u);
    return (unsigned short)(u >> 16);
}
static __device__ __forceinline__ float bflo(unsigned int u) { return __uint_as_float(u << 16); }
static __device__ __forceinline__ float bfhi(unsigned int u) { return __uint_as_float(u & 0xFFFF0000u); }

// one-instruction RNE pair conversion (same rounding as f2bf), replaces ~9 inst
static __device__ __forceinline__ unsigned int cvt_pk_bf16(float lo, float hi) {
    unsigned int r;
    asm("v_cvt_pk_bf16_f32 %0, %1, %2" : "=v"(r) : "v"(lo), "v"(hi));
    return r;
}

// fast silu: x * rcp(1 + 2^(-x*log2e)) -> v_exp_f32 + v_rcp_f32, ~5 inst
static __device__ __forceinline__ float silu_f(float x) {
    float e = __builtin_amdgcn_exp2f(x * -1.44269504f);
    return x * __builtin_amdgcn_rcpf(1.0f + e);
}

// ---- fused one-shot prep (blocks < 1408) + src histogram + agg zero ----
#define PREP_BLOCKS 1408
#define HIST_BLOCKS 3125
#define ZERO_BLOCKS 6250   // N*HDIM*4B / (256*16B) = 6250 exact
__global__ void prep_hist_kernel(const float* __restrict__ ew1, const float* __restrict__ ew2,
                                 const float* __restrict__ nw1, const float* __restrict__ nw2,
                                 const float* __restrict__ eb1, const float* __restrict__ lattices,
                                 const int* __restrict__ eidx,
                                 unsigned short* __restrict__ W1aT, unsigned short* __restrict__ W1bT,
                                 unsigned short* __restrict__ W2t, unsigned short* __restrict__ N1t,
                                 unsigned short* __restrict__ N2t, unsigned short* __restrict__ Lb,
                                 int* __restrict__ buf, float* __restrict__ agg) {
    const int bid = blockIdx.x;
    if (bid >= PREP_BLOCKS + HIST_BLOCKS) {
        // zero agg (= d_out) so edge_kernel atomics start from 0
        const int idx = (bid - PREP_BLOCKS - HIST_BLOCKS) * 256 + threadIdx.x;
        ((float4*)agg)[idx] = make_float4(0.f, 0.f, 0.f, 0.f);
        return;
    }
    if (bid >= PREP_BLOCKS) {
        int e = (bid - PREP_BLOCKS) * 256 + threadIdx.x;
        if (e < N_EDGES) atomicAdd(&buf[eidx[e]], 1);
        return;
    }
    int i = bid * 256 + threadIdx.x;
    if (i < 16384) {
        int n = i >> 7, k = i & 127;
        W1aT[i] = f2bf(ew1[k * 128 + n]);
    } else if (i < 32768) {
        int j = i - 16384; int n = j >> 7, k = j & 127;
        W1bT[j] = f2bf(ew1[(128 + k) * 128 + n]);
    } else if (i < 49152) {
        int j = i - 32768; int n = j >> 7, k = j & 127;
        W2t[j] = f2bf(ew2[k * 128 + n]);
    } else if (i < 81920) {
        int j = i - 49152; int n = j >> 8, k = j & 255;
        N1t[j] = f2bf(nw1[k * 128 + n]);
    } else if (i < 98304) {
        int j = i - 81920; int n = j >> 7, k = j & 127;
        N2t[j] = f2bf(nw2[k * 128 + n]);
    } else if (i < 98304 + 262144) {
        int j = i - 98304; int g = j >> 7, c = j & 127;
        float s = eb1[c];
#pragma unroll
        for (int t = 0; t < 6; ++t) s += lattices[g * 6 + t] * ew1[(256 + t) * 128 + c];
        Lb[j] = f2bf(s);
    }
}

// single-block scan; wave-shuffle scan at 1024 threads (best measured: R7
// non-edge 296us; the 256-thread fused variant regressed +27us in R8).
__global__ __launch_bounds__(1024) void scan_kernel(int* __restrict__ buf) {
    constexpr int CH = 12288;
    __shared__ int lds[CH];
    __shared__ int wpart[16];
    __shared__ int carry_s;
    const int t = threadIdx.x;
    const int wave = t >> 6, lane = t & 63;
    if (t == 0) carry_s = 0;
    __syncthreads();
#pragma unroll 1
    for (int base = 0; base < N_NODES; base += CH) {
#pragma unroll
        for (int k = 0; k < CH / 1024; ++k) {
            int f = k * 1024 + t;
            lds[f] = (base + f < N_NODES) ? buf[base + f] : 0;
        }
        __syncthreads();
        int loc[12];
        int s = 0;
#pragma unroll
        for (int i = 0; i < 12; ++i) { loc[i] = lds[t * 12 + i]; s += loc[i]; }
        // wave-level inclusive scan of s (no barriers)
        int ps = s;
#pragma unroll
        for (int off = 1; off < 64; off <<= 1) {
            int v = __shfl_up(ps, off);
            if (lane >= off) ps += v;
        }
        if (lane == 63) wpart[wave] = ps;   // wave total
        __syncthreads();
        if (t == 0) {
            int r = carry_s;
#pragma unroll
            for (int i = 0; i < 16; ++i) { int v = wpart[i]; wpart[i] = r; r += v; }
            carry_s = r;                     // new carry = old + chunk total
        }
        __syncthreads();
        int run = wpart[wave] + (ps - s);    // exclusive prefix for this thread
#pragma unroll
        for (int i = 0; i < 12; ++i) { int tmp = loc[i]; lds[t * 12 + i] = run; run += tmp; }
        __syncthreads();
#pragma unroll
        for (int k = 0; k < CH / 1024; ++k) {
            int f = k * 1024 + t;
            if (base + f < N_NODES) buf[base + f] = lds[f];
        }
        __syncthreads();
    }
}

// ---- fused perm scatter (blocks < 3125) + pq precompute (blocks >= 3125) ----
#define PERM_BLOCKS2 3125
#define PQ_BLOCKS ((N_NODES + 63) / 64)
__global__ __launch_bounds__(256, 4) void perm_pq_kernel(
    const int* __restrict__ eidx, const int* __restrict__ e2g,
    const float* __restrict__ frac_diff, int* __restrict__ buf,
    unsigned short* __restrict__ perm_lo, unsigned char* __restrict__ perm_hi,
    uint4* __restrict__ rec, const int packed,
    const float* __restrict__ nf, const unsigned short* __restrict__ W1aT,
    const unsigned short* __restrict__ W1bT,
    unsigned short* __restrict__ P, unsigned short* __restrict__ Qm) {
    constexpr int SA = 136;
    __shared__ unsigned short sm[64 * SA];
    const int bid = blockIdx.x;
    const int tid = threadIdx.x;

    if (bid < PERM_BLOCKS2) {
        int e = bid * 256 + tid;
        if (e < N_EDGES) {
            int s = eidx[e];
            int pos = atomicAdd(&buf[s], 1);
            if (packed) {
                int d = eidx[N_EDGES + e];
                int g = e2g[e];
                unsigned int w0 = (unsigned int)s | ((unsigned int)d << 16);
                unsigned int w1 = (unsigned int)g | ((unsigned int)f2bf(frac_diff[3 * e]) << 16);
                unsigned int w2 = (unsigned int)f2bf(frac_diff[3 * e + 1]) |
                                  ((unsigned int)f2bf(frac_diff[3 * e + 2]) << 16);
                rec[pos] = make_uint4(w0, w1, w2, 0u);
            } else {
                perm_lo[pos] = (unsigned short)(e & 0xFFFF);
                perm_hi[pos] = (unsigned char)(e >> 16);
            }
        }
        return;
    }

    const int n0 = (bid - PERM_BLOCKS2) * 64;
    const int mrow = tid >> 2, q = tid & 3;
    {
        const int node = n0 + mrow;
        unsigned short* row = sm + mrow * SA + q * 32;
        if (node < N_NODES) {
            const float4* a4 = (const float4*)(nf + (size_t)node * HDIM) + q * 8;
#pragma unroll
            for (int j = 0; j < 8; ++j) {
                float4 v = a4[j];
                *(ushort4*)(row + 4 * j) = make_ushort4(f2bf(v.x), f2bf(v.y), f2bf(v.z), f2bf(v.w));
            }
        } else {
#pragma unroll
            for (int j = 0; j < 8; ++j) *(ushort4*)(row + 4 * j) = make_ushort4(0, 0, 0, 0);
        }
    }
    __syncthreads();

    const int wave = tid >> 6, lane = tid & 63;
    const int lr = lane & 15, kq = lane >> 4;
    f32x4 acca[8] = {}, accb[8] = {};
    const int arow = (wave * 16 + lr) * SA;
#pragma unroll
    for (int ks = 0; ks < 128; ks += 32) {
        bf16x8 a = *(const bf16x8*)(sm + arow + ks + kq * 8);
#pragma unroll
        for (int nt = 0; nt < 8; ++nt) {
            bf16x8 ba = *(const bf16x8*)(W1aT + (nt * 16 + lr) * 128 + ks + kq * 8);
            acca[nt] = __builtin_amdgcn_mfma_f32_16x16x32_bf16(a, ba, acca[nt], 0, 0, 0);
            bf16x8 bb = *(const bf16x8*)(W1bT + (nt * 16 + lr) * 128 + ks + kq * 8);
            accb[nt] = __builtin_amdgcn_mfma_f32_16x16x32_bf16(a, bb, accb[nt], 0, 0, 0);
        }
    }
    __syncthreads();

    const int node = n0 + mrow;
#pragma unroll
    for (int nt = 0; nt < 8; ++nt) {
        const int col = nt * 16 + lr;
#pragma unroll
        for (int r = 0; r < 4; ++r)
            sm[(wave * 16 + kq * 4 + r) * SA + col] = f2bf(acca[nt][r]);
    }
    __syncthreads();
    if (node < N_NODES) {
        uint4* dst = (uint4*)(P + (size_t)node * HDIM + q * 32);
        const uint4* srcp = (const uint4*)(sm + mrow * SA + q * 32);
#pragma unroll
        for (int j = 0; j < 4; ++j) dst[j] = srcp[j];
    }
    __syncthreads();
#pragma unroll
    for (int nt = 0; nt < 8; ++nt) {
        const int col = nt * 16 + lr;
#pragma unroll
        for (int r = 0; r < 4; ++r)
            sm[(wave * 16 + kq * 4 + r) * SA + col] = f2bf(accb[nt][r]);
    }
    __syncthreads();
    if (node < N_NODES) {
        uint4* dst = (uint4*)(Qm + (size_t)node * HDIM + q * 32);
        const uint4* srcp = (const uint4*)(sm + mrow * SA + q * 32);
#pragma unroll
        for (int j = 0; j < 4; ++j) dst[j] = srcp[j];
    }
}

// ================= edge kernel helpers (32x32 MFMA path) =================

// build A-fragments from gathered P/Q/Lb rows + fd * (bf16 weights from LDS)
static __device__ __forceinline__ void build_afrag(
    const uint4* pu, const uint4* qu, const uint4* lu,
    float f0, float f1, float f2,
    const unsigned int* wlds, int hi, bf16x8* afrag) {
#pragma unroll
    for (int kk = 0; kk < 8; ++kk) {
        const unsigned int* wl = wlds + (kk * 2 + hi) * 12;
        const uint4 w0v = *(const uint4*)(wl);
        const uint4 w1v = *(const uint4*)(wl + 4);
        const uint4 w2v = *(const uint4*)(wl + 8);
        const unsigned int* pw = (const unsigned int*)&pu[kk];
        const unsigned int* qw = (const unsigned int*)&qu[kk];
        const unsigned int* lw = (const unsigned int*)&lu[kk];
        const unsigned int* w0w = (const unsigned int*)&w0v;
        const unsigned int* w1w = (const unsigned int*)&w1v;
        const unsigned int* w2w = (const unsigned int*)&w2v;
        unsigned int ow[4];
#pragma unroll
        for (int w = 0; w < 4; ++w) {
            float x0 = bflo(pw[w]) + bflo(qw[w]) + bflo(lw[w])
                     + f0 * bflo(w0w[w]) + f1 * bflo(w1w[w]) + f2 * bflo(w2w[w]);
            float x1 = bfhi(pw[w]) + bfhi(qw[w]) + bfhi(lw[w])
                     + f0 * bfhi(w0w[w]) + f1 * bfhi(w1w[w]) + f2 * bfhi(w2w[w]);
            ow[w] = cvt_pk_bf16(silu_f(x0), silu_f(x1));
        }
        afrag[kk] = *(bf16x8*)ow;
    }
}

// NOTE: no s_setprio here — R7 measured it pins the schedule and causes a
// mild scratch spill (+43MB TCC traffic, +25us). Plain cluster is fastest.
static __device__ __forceinline__ void do_mfma(
    const bf16x8* afrag, const unsigned short* __restrict__ W2t,
    int row, int hi, f32x16* acc) {
#pragma unroll
    for (int kk = 0; kk < 8; ++kk) {
#pragma unroll
        for (int t4 = 0; t4 < 4; ++t4) {
            bf16x8 bb = *(const bf16x8*)(W2t + (t4 * 32 + row) * 128 + kk * 16 + hi * 8);
            acc[t4] = __builtin_amdgcn_mfma_f32_32x32x16_bf16(afrag[kk], bb, acc[t4], 0, 0, 0);
        }
    }
}

// segmented reduction over 32 sorted rows on the 32x32 C layout
// (row = (reg&3) + 8*(reg>>2) + 4*hi); hi-halves merged via shfl_xor.
// seg[a,b] emitted as +prefix[b] to src[b], -prefix[a-1] to src[a]
static __device__ __forceinline__ void epilogue(
    const f32x16* acc, const int* sc, const int* snq,
    int row, int hi, const float* __restrict__ b2, float* __restrict__ agg) {
#pragma unroll
    for (int t4 = 0; t4 < 4; ++t4) {
        const int col = t4 * 32 + row;
        const float bias = b2[col];
        float p[16], tq[4], to[4];
#pragma unroll
        for (int rq = 0; rq < 4; ++rq) {
            float s0 = silu_f(acc[t4][4 * rq + 0] + bias);
            float s1 = silu_f(acc[t4][4 * rq + 1] + bias);
            float s2 = silu_f(acc[t4][4 * rq + 2] + bias);
            float s3 = silu_f(acc[t4][4 * rq + 3] + bias);
            p[4 * rq + 0] = s0;
            p[4 * rq + 1] = s0 + s1;
            p[4 * rq + 2] = p[4 * rq + 1] + s2;
            p[4 * rq + 3] = p[4 * rq + 2] + s3;
            tq[rq] = p[4 * rq + 3];
            to[rq] = __shfl_xor(tq[rq], 32);
        }
        float cum = 0.f;
#pragma unroll
        for (int rq = 0; rq < 4; ++rq) {
            const float off = cum + (hi ? to[rq] : 0.f);
            cum += tq[rq] + to[rq];
#pragma unroll
            for (int i = 0; i < 4; ++i) {
                const int r = 4 * rq + i;
                const float val = p[r] + off;
                const int myrow = 4 * (2 * rq + hi) + i;
                const bool lastg = (myrow == 31);
                const int nxt = (i < 3) ? sc[r + 1] : snq[rq];
                const bool bnd = lastg || (sc[r] != nxt);
                if (bnd) {
                    atomicAdd(&agg[(size_t)sc[r] * HDIM + col], val);
                    if (!lastg) atomicAdd(&agg[(size_t)nxt * HDIM + col], -val);
                }
            }
        }
    }
}

// ---- edge kernel: 64 edges/wave = two straight-line 32-edge chunks (best
// measured: 211us at 2 waves/SIMD, launch_bounds(256,2)). This config is a
// measured local optimum, confirmed from five perturbation directions:
//   4-chunk (R5): spill. per-tile fusion (R6): spill. setprio (R7): spill.
//   min-waves=3 cap (R10): spill (WRITE 61.7->355MB, 211->270us).
//   rotating loop (R1): serialized.
// Register economics are irreducible: 96 prefetch regs (chunk-B gathers) +
// 64 AGPR acc + working set ~= 190 -> occupancy quantum = 2 waves/SIMD.
#define EDGE_NWG (N_EDGES / 256)   // 3125 blocks of 4 waves x 64 edges
template <bool PACKED>
static __device__ __forceinline__ void fetch_meta(
    int i, const uint4* __restrict__ rec, const int* __restrict__ eidx,
    const int* __restrict__ e2g, const float* __restrict__ frac_diff,
    const unsigned short* __restrict__ perm_lo, const unsigned char* __restrict__ perm_hi,
    int& src, int& dst, int& g, float& f0, float& f1, float& f2) {
    if (PACKED) {
        const uint4 rv = rec[i];
        src = rv.x & 0xFFFF;
        dst = rv.x >> 16;
        g = rv.y & 0xFFFF;
        f0 = bfhi(rv.y);
        f1 = bflo(rv.z);
        f2 = bfhi(rv.z);
    } else {
        const int e = (int)perm_lo[i] | ((int)perm_hi[i] << 16);
        src = eidx[e];
        dst = eidx[N_EDGES + e];
        g = e2g[e];
        f0 = frac_diff[3 * e];
        f1 = frac_diff[3 * e + 1];
        f2 = frac_diff[3 * e + 2];
    }
}

static __device__ __forceinline__ void gather_rows(
    const unsigned short* __restrict__ P, const unsigned short* __restrict__ Qm,
    const unsigned short* __restrict__ Lb,
    int src, int dst, int g, int hi, uint4* pu, uint4* qu, uint4* lu) {
    const size_t pr = (size_t)src * HDIM, qr = (size_t)dst * HDIM, lr = (size_t)g * HDIM;
#pragma unroll
    for (int kk = 0; kk < 8; ++kk) {
        const int c0 = kk * 16 + hi * 8;
        pu[kk] = *(const uint4*)(P + pr + c0);
        qu[kk] = *(const uint4*)(Qm + qr + c0);
        lu[kk] = *(const uint4*)(Lb + lr + c0);
    }
}

static __device__ __forceinline__ void make_sc(int src, int hi, int* sc, int* snq) {
#pragma unroll
    for (int r = 0; r < 16; ++r) sc[r] = __shfl(src, (r & 3) + 8 * (r >> 2) + 4 * hi);
#pragma unroll
    for (int j = 0; j < 4; ++j) snq[j] = __shfl(src, (4 * (2 * j + hi) + 4) & 31);
}

template <bool PACKED>
__global__ __launch_bounds__(256, 2) void edge_kernel(
    const unsigned short* __restrict__ P, const unsigned short* __restrict__ Qm,
    const unsigned short* __restrict__ Lb, const float* __restrict__ frac_diff,
    const int* __restrict__ eidx, const int* __restrict__ e2g,
    const unsigned short* __restrict__ perm_lo, const unsigned char* __restrict__ perm_hi,
    const uint4* __restrict__ rec,
    const float* __restrict__ e_w1, const unsigned short* __restrict__ W2t,
    const float* __restrict__ b2, float* __restrict__ agg) {
    // fd-weight columns of e_w1 (rows 262..264) as bf16 pairs in LDS:
    // layout [kk][hi][rw][4 dwords]; reads are 2-address broadcasts (free).
    __shared__ __align__(16) unsigned int wlds[192];
    const int tid = threadIdx.x;
    {
        const float* wrbase = e_w1 + 262 * HDIM;
        if (tid < 192) {
            const int w = tid & 3, rw = (tid >> 2) % 3, hi = (tid / 12) & 1, kk = tid / 24;
            const int c = kk * 16 + hi * 8 + 2 * w;
            wlds[((kk * 2 + hi) * 3 + rw) * 4 + w] =
                (unsigned int)f2bf(wrbase[rw * HDIM + c]) |
                ((unsigned int)f2bf(wrbase[rw * HDIM + c + 1]) << 16);
        }
    }
    __syncthreads();

    const int wv = tid >> 6, lane = tid & 63;
    const int row = lane & 31, hi = lane >> 5;
    const int base = (blockIdx.x * 4 + wv) * 64;   // this wave's 64 edges

    // ---- metadata for both chunks ----
    int srcA, dstA, gA; float fA0, fA1, fA2;
    fetch_meta<PACKED>(base + row, rec, eidx, e2g, frac_diff, perm_lo, perm_hi,
                       srcA, dstA, gA, fA0, fA1, fA2);
    int srcB, dstB, gB; float fB0, fB1, fB2;
    fetch_meta<PACKED>(base + 32 + row, rec, eidx, e2g, frac_diff, perm_lo, perm_hi,
                       srcB, dstB, gB, fB0, fB1, fB2);

    // ---- chunk A+B gathers up-front (B's latency hides under A compute) ----
    uint4 puA[8], quA[8], luA[8];
    gather_rows(P, Qm, Lb, srcA, dstA, gA, hi, puA, quA, luA);
    uint4 puB[8], quB[8], luB[8];
    gather_rows(P, Qm, Lb, srcB, dstB, gB, hi, puB, quB, luB);

    // ---- chunk A: afrag -> MFMA -> epilogue ----
    {
        bf16x8 afrag[8];
        build_afrag(puA, quA, luA, fA0, fA1, fA2, wlds, hi, afrag);
        int sc[16], snq[4];
        make_sc(srcA, hi, sc, snq);
        f32x16 acc[4] = {};
        do_mfma(afrag, W2t, row, hi, acc);
        epilogue(acc, sc, snq, row, hi, b2, agg);
    }

    // ---- chunk B: afrag -> MFMA -> epilogue ----
    {
        bf16x8 afrag[8];
        build_afrag(puB, quB, luB, fB0, fB1, fB2, wlds, hi, afrag);
        int sc[16], snq[4];
        make_sc(srcB, hi, sc, snq);
        f32x16 acc[4] = {};
        do_mfma(afrag, W2t, row, hi, acc);
        epilogue(acc, sc, snq, row, hi, b2, agg);
    }
}

// ---- node MLP: h = concat(nf, agg/cnt) -> silu -> silu -> + nf (agg aliases out) ----
__global__ __launch_bounds__(256, 4) void node_kernel(
    const float* __restrict__ nf, const float* __restrict__ agg,
    const int* __restrict__ buf,
    const unsigned short* __restrict__ N1t, const float* __restrict__ b1,
    const unsigned short* __restrict__ N2t, const float* __restrict__ b2,
    float* __restrict__ out) {
    constexpr int SA = 264;
    constexpr int S2 = 136;
    constexpr int SFo = 132;
    __shared__ unsigned short sm[64 * SA];
    float* smf = (float*)sm;

    const int tid = threadIdx.x;
    const int n0 = blockIdx.x * 64;
    const int mrow = tid >> 2, q = tid & 3;
    {
        const int node = n0 + mrow;
        unsigned short* row = sm + mrow * SA;
        const int cbq = q * 32;
        if (node < N_NODES) {
            const int c = buf[node] - (node ? buf[node - 1] : 0);
            const float inv = 1.0f / (float)max(c, 1);
            const float4* a4 = (const float4*)(nf + (size_t)node * HDIM) + q * 8;
            const float4* g4 = (const float4*)(agg + (size_t)node * HDIM) + q * 8;
#pragma unroll
            for (int j = 0; j < 8; ++j) {
                float4 v = a4[j];
                *(ushort4*)(row + cbq + 4 * j) =
                    make_ushort4(f2bf(v.x), f2bf(v.y), f2bf(v.z), f2bf(v.w));
                float4 g = g4[j];
                *(ushort4*)(row + HDIM + cbq + 4 * j) =
                    make_ushort4(f2bf(g.x * inv), f2bf(g.y * inv), f2bf(g.z * inv), f2bf(g.w * inv));
            }
        } else {
#pragma unroll
            for (int j = 0; j < 8; ++j) {
                *(ushort4*)(row + cbq + 4 * j) = make_ushort4(0, 0, 0, 0);
                *(ushort4*)(row + HDIM + cbq + 4 * j) = make_ushort4(0, 0, 0, 0);
            }
        }
    }
    __syncthreads();

    const int wave = tid >> 6, lane = tid & 63;
    const int lr = lane & 15, kq = lane >> 4;

    f32x4 acc[8] = {};
    const int arow = (wave * 16 + lr) * SA;
#pragma unroll
    for (int ks = 0; ks < 256; ks += 32) {
        bf16x8 a = *(const bf16x8*)(sm + arow + ks + kq * 8);
#pragma unroll
        for (int nt = 0; nt < 8; ++nt) {
            bf16x8 bb = *(const bf16x8*)(N1t + (nt * 16 + lr) * 256 + ks + kq * 8);
            acc[nt] = __builtin_amdgcn_mfma_f32_16x16x32_bf16(a, bb, acc[nt], 0, 0, 0);
        }
    }
    __syncthreads();

#pragma unroll
    for (int nt = 0; nt < 8; ++nt) {
        const int col = nt * 16 + lr;
        const float bias = b1[col];
#pragma unroll
        for (int r = 0; r < 4; ++r) {
            const int mm = wave * 16 + kq * 4 + r;
            sm[mm * S2 + col] = f2bf(silu_f(acc[nt][r] + bias));
        }
    }
    __syncthreads();

    f32x4 acc2[8] = {};
    const int arow2 = (wave * 16 + lr) * S2;
#pragma unroll
    for (int ks = 0; ks < 128; ks += 32) {
        bf16x8 a = *(const bf16x8*)(sm + arow2 + ks + kq * 8);
#pragma unroll
        for (int nt = 0; nt < 8; ++nt) {
            bf16x8 bb = *(const bf16x8*)(N2t + (nt * 16 + lr) * 128 + ks + kq * 8);
            acc2[nt] = __builtin_amdgcn_mfma_f32_16x16x32_bf16(a, bb, acc2[nt], 0, 0, 0);
        }
    }
    __syncthreads();

#pragma unroll
    for (int nt = 0; nt < 8; ++nt) {
        const int col = nt * 16 + lr;
        const float bias = b2[col];
#pragma unroll
        for (int r = 0; r < 4; ++r) {
            const int mm = wave * 16 + kq * 4 + r;
            smf[mm * SFo + col] = silu_f(acc2[nt][r] + bias);
        }
    }
    __syncthreads();
    {
        const int node = n0 + mrow;
        if (node < N_NODES) {
            const float4* nfr = (const float4*)(nf + (size_t)node * HDIM) + q * 8;
            float4* outr = (float4*)(out + (size_t)node * HDIM) + q * 8;
            const float* st = smf + mrow * SFo + q * 32;
#pragma unroll
            for (int j = 0; j < 8; ++j) {
                float4 v = nfr[j];
                float4 s4 = *(const float4*)(st + 4 * j);
                v.x += s4.x; v.y += s4.y; v.z += s4.z; v.w += s4.w;
                outr[j] = v;
            }
        }
    }
}

extern "C" void kernel_launch(void* const* d_in, const int* in_sizes, int n_in,
                              void* d_out, int out_size, void* d_ws, size_t ws_size,
                              hipStream_t stream) {
    const float* node_features = (const float*)d_in[0];
    const float* lattices = (const float*)d_in[2];
    const float* frac_diff = (const float*)d_in[3];
    const int* edge_index = (const int*)d_in[4];
    const int* edge2graph = (const int*)d_in[5];
    const float* e_w1 = (const float*)d_in[6];
    const float* e_b1 = (const float*)d_in[7];
    const float* e_w2 = (const float*)d_in[8];
    const float* e_b2 = (const float*)d_in[9];
    const float* n_w1 = (const float*)d_in[10];
    const float* n_b1 = (const float*)d_in[11];
    const float* n_w2 = (const float*)d_in[12];
    const float* n_b2 = (const float*)d_in[13];

    // workspace layout (bytes):
    //   0         W1aT | 32768 W1bT | 65536 W2t | 98304 N1t | 163840 N2t
    //   196608    Lb   (G*128 bf16)
    //   720896    P    (N*128 bf16, 12.8MB)
    //   13520896  Q    (N*128 bf16, 12.8MB)
    //   26320896  buf  (N int)
    //   26520896  perm_lo (E u16) | 28120896 perm_hi (E u8)   [fallback path]
    //   28920896  rec  (E x 16B packed sorted metadata)       [packed path, if ws fits]
    // agg lives in d_out (node_kernel reads its own rows before overwriting).
    char* ws = (char*)d_ws;
    unsigned short* W1aT = (unsigned short*)(ws);
    unsigned short* W1bT = (unsigned short*)(ws + 32768);
    unsigned short* W2t  = (unsigned short*)(ws + 65536);
    unsigned short* N1t  = (unsigned short*)(ws + 98304);
    unsigned short* N2t  = (unsigned short*)(ws + 163840);
    unsigned short* Lb   = (unsigned short*)(ws + 196608);
    unsigned short* P    = (unsigned short*)(ws + 720896);
    unsigned short* Qm   = (unsigned short*)(ws + 13520896);
    int* buf             = (int*)(ws + 26320896);
    unsigned short* perm_lo = (unsigned short*)(ws + 26520896);
    unsigned char* perm_hi  = (unsigned char*)(ws + 28120896);
    uint4* rec           = (uint4*)(ws + 28920896);
    float* agg = (float*)d_out;

    // ws_size is fixed for the session -> this branch is deterministic (graph-safe)
    const int packed = (ws_size >= 28920896 + (size_t)N_EDGES * 16) ? 1 : 0;

    hipMemsetAsync(buf, 0, (size_t)N_NODES * 4, stream);

    prep_hist_kernel<<<PREP_BLOCKS + HIST_BLOCKS + ZERO_BLOCKS, 256, 0, stream>>>(
        e_w1, e_w2, n_w1, n_w2, e_b1, lattices, edge_index,
        W1aT, W1bT, W2t, N1t, N2t, Lb, buf, agg);

    scan_kernel<<<1, 1024, 0, stream>>>(buf);

    perm_pq_kernel<<<PERM_BLOCKS2 + PQ_BLOCKS, 256, 0, stream>>>(
        edge_index, edge2graph, frac_diff, buf, perm_lo, perm_hi, rec, packed,
        node_features, W1aT, W1bT, P, Qm);

    if (packed) {
        edge_kernel<true><<<EDGE_NWG, 256, 0, stream>>>(
            P, Qm, Lb, frac_diff, edge_index, edge2graph, perm_lo, perm_hi, rec,
            e_w1, W2t, e_b2, agg);
    } else {
        edge_kernel<false><<<EDGE_NWG, 256, 0, stream>>>(
            P, Qm, Lb, frac_diff, edge_index, edge2graph, perm_lo, perm_hi, rec,
            e_w1, W2t, e_b2, agg);
    }

    node_kernel<<<(N_NODES + 63) / 64, 256, 0, stream>>>(
        node_features, agg, buf, N1t, n_b1, N2t, n_b2, (float*)d_out);
}

// Round 12
// 502.261 us; speedup vs baseline: 1.1191x; 1.0083x over previous
//
#include <hip/hip_runtime.h>

#define N_NODES 50000
#define N_EDGES 800000
#define HDIM 128
#define N_GRAPH 2048

typedef __bf16 bf16x8 __attribute__((ext_vector_type(8)));
typedef float f32x4 __attribute__((ext_vector_type(4)));
typedef float f32x16 __attribute__((ext_vector_type(16)));

// round-to-nearest-even fp32 -> bf16
static __device__ __forceinline__ unsigned short f2bf(float f) {
    unsigned int u = __float_as_uint(f);
    u += 0x7fffu + ((u >> 16) & 1u);
    return (unsigned short)(u >> 16);
}
static __device__ __forceinline__ float bflo(unsigned int u) { return __uint_as_float(u << 16); }
static __device__ __forceinline__ float bfhi(unsigned int u) { return __uint_as_float(u & 0xFFFF0000u); }

// one-instruction RNE pair conversion (same rounding as f2bf), replaces ~9 inst
static __device__ __forceinline__ unsigned int cvt_pk_bf16(float lo, float hi) {
    unsigned int r;
    asm("v_cvt_pk_bf16_f32 %0, %1, %2" : "=v"(r) : "v"(lo), "v"(hi));
    return r;
}

// fast silu: x * rcp(1 + 2^(-x*log2e)) -> v_exp_f32 + v_rcp_f32, ~5 inst
static __device__ __forceinline__ float silu_f(float x) {
    float e = __builtin_amdgcn_exp2f(x * -1.44269504f);
    return x * __builtin_amdgcn_rcpf(1.0f + e);
}

// ---- fused one-shot prep (blocks < 1408) + src histogram + agg zero ----
#define PREP_BLOCKS 1408
#define HIST_BLOCKS 3125
#define ZERO_BLOCKS 6250   // N*HDIM*4B / (256*16B) = 6250 exact
__global__ void prep_hist_kernel(const float* __restrict__ ew1, const float* __restrict__ ew2,
                                 const float* __restrict__ nw1, const float* __restrict__ nw2,
                                 const float* __restrict__ eb1, const float* __restrict__ lattices,
                                 const int* __restrict__ eidx,
                                 unsigned short* __restrict__ W1aT, unsigned short* __restrict__ W1bT,
                                 unsigned short* __restrict__ W2t, unsigned short* __restrict__ N1t,
                                 unsigned short* __restrict__ N2t, unsigned short* __restrict__ Lb,
                                 int* __restrict__ buf, float* __restrict__ agg) {
    const int bid = blockIdx.x;
    if (bid >= PREP_BLOCKS + HIST_BLOCKS) {
        // zero agg (= d_out) so edge_kernel atomics start from 0
        const int idx = (bid - PREP_BLOCKS - HIST_BLOCKS) * 256 + threadIdx.x;
        ((float4*)agg)[idx] = make_float4(0.f, 0.f, 0.f, 0.f);
        return;
    }
    if (bid >= PREP_BLOCKS) {
        int e = (bid - PREP_BLOCKS) * 256 + threadIdx.x;
        if (e < N_EDGES) atomicAdd(&buf[eidx[e]], 1);
        return;
    }
    int i = bid * 256 + threadIdx.x;
    if (i < 16384) {
        int n = i >> 7, k = i & 127;
        W1aT[i] = f2bf(ew1[k * 128 + n]);
    } else if (i < 32768) {
        int j = i - 16384; int n = j >> 7, k = j & 127;
        W1bT[j] = f2bf(ew1[(128 + k) * 128 + n]);
    } else if (i < 49152) {
        int j = i - 32768; int n = j >> 7, k = j & 127;
        W2t[j] = f2bf(ew2[k * 128 + n]);
    } else if (i < 81920) {
        int j = i - 49152; int n = j >> 8, k = j & 255;
        N1t[j] = f2bf(nw1[k * 128 + n]);
    } else if (i < 98304) {
        int j = i - 81920; int n = j >> 7, k = j & 127;
        N2t[j] = f2bf(nw2[k * 128 + n]);
    } else if (i < 98304 + 262144) {
        int j = i - 98304; int g = j >> 7, c = j & 127;
        float s = eb1[c];
#pragma unroll
        for (int t = 0; t < 6; ++t) s += lattices[g * 6 + t] * ew1[(256 + t) * 128 + c];
        Lb[j] = f2bf(s);
    }
}

// single-block scan; wave-shuffle scan at 1024 threads (best measured: R7
// non-edge 296us; the 256-thread fused variant regressed +27us in R8).
__global__ __launch_bounds__(1024) void scan_kernel(int* __restrict__ buf) {
    constexpr int CH = 12288;
    __shared__ int lds[CH];
    __shared__ int wpart[16];
    __shared__ int carry_s;
    const int t = threadIdx.x;
    const int wave = t >> 6, lane = t & 63;
    if (t == 0) carry_s = 0;
    __syncthreads();
#pragma unroll 1
    for (int base = 0; base < N_NODES; base += CH) {
#pragma unroll
        for (int k = 0; k < CH / 1024; ++k) {
            int f = k * 1024 + t;
            lds[f] = (base + f < N_NODES) ? buf[base + f] : 0;
        }
        __syncthreads();
        int loc[12];
        int s = 0;
#pragma unroll
        for (int i = 0; i < 12; ++i) { loc[i] = lds[t * 12 + i]; s += loc[i]; }
        // wave-level inclusive scan of s (no barriers)
        int ps = s;
#pragma unroll
        for (int off = 1; off < 64; off <<= 1) {
            int v = __shfl_up(ps, off);
            if (lane >= off) ps += v;
        }
        if (lane == 63) wpart[wave] = ps;   // wave total
        __syncthreads();
        if (t == 0) {
            int r = carry_s;
#pragma unroll
            for (int i = 0; i < 16; ++i) { int v = wpart[i]; wpart[i] = r; r += v; }
            carry_s = r;                     // new carry = old + chunk total
        }
        __syncthreads();
        int run = wpart[wave] + (ps - s);    // exclusive prefix for this thread
#pragma unroll
        for (int i = 0; i < 12; ++i) { int tmp = loc[i]; lds[t * 12 + i] = run; run += tmp; }
        __syncthreads();
#pragma unroll
        for (int k = 0; k < CH / 1024; ++k) {
            int f = k * 1024 + t;
            if (base + f < N_NODES) buf[base + f] = lds[f];
        }
        __syncthreads();
    }
}

// ---- fused perm scatter (blocks < 3125) + pq precompute (blocks >= 3125) ----
#define PERM_BLOCKS2 3125
#define PQ_BLOCKS ((N_NODES + 63) / 64)
__global__ __launch_bounds__(256, 4) void perm_pq_kernel(
    const int* __restrict__ eidx, const int* __restrict__ e2g,
    const float* __restrict__ frac_diff, int* __restrict__ buf,
    unsigned short* __restrict__ perm_lo, unsigned char* __restrict__ perm_hi,
    uint4* __restrict__ rec, const int packed,
    const float* __restrict__ nf, const unsigned short* __restrict__ W1aT,
    const unsigned short* __restrict__ W1bT,
    unsigned short* __restrict__ P, unsigned short* __restrict__ Qm) {
    constexpr int SA = 136;
    __shared__ unsigned short sm[64 * SA];
    const int bid = blockIdx.x;
    const int tid = threadIdx.x;

    if (bid < PERM_BLOCKS2) {
        int e = bid * 256 + tid;
        if (e < N_EDGES) {
            int s = eidx[e];
            int pos = atomicAdd(&buf[s], 1);
            if (packed) {
                int d = eidx[N_EDGES + e];
                int g = e2g[e];
                unsigned int w0 = (unsigned int)s | ((unsigned int)d << 16);
                unsigned int w1 = (unsigned int)g | ((unsigned int)f2bf(frac_diff[3 * e]) << 16);
                unsigned int w2 = (unsigned int)f2bf(frac_diff[3 * e + 1]) |
                                  ((unsigned int)f2bf(frac_diff[3 * e + 2]) << 16);
                rec[pos] = make_uint4(w0, w1, w2, 0u);
            } else {
                perm_lo[pos] = (unsigned short)(e & 0xFFFF);
                perm_hi[pos] = (unsigned char)(e >> 16);
            }
        }
        return;
    }

    const int n0 = (bid - PERM_BLOCKS2) * 64;
    const int mrow = tid >> 2, q = tid & 3;
    {
        const int node = n0 + mrow;
        unsigned short* row = sm + mrow * SA + q * 32;
        if (node < N_NODES) {
            const float4* a4 = (const float4*)(nf + (size_t)node * HDIM) + q * 8;
#pragma unroll
            for (int j = 0; j < 8; ++j) {
                float4 v = a4[j];
                *(ushort4*)(row + 4 * j) = make_ushort4(f2bf(v.x), f2bf(v.y), f2bf(v.z), f2bf(v.w));
            }
        } else {
#pragma unroll
            for (int j = 0; j < 8; ++j) *(ushort4*)(row + 4 * j) = make_ushort4(0, 0, 0, 0);
        }
    }
    __syncthreads();

    const int wave = tid >> 6, lane = tid & 63;
    const int lr = lane & 15, kq = lane >> 4;
    f32x4 acca[8] = {}, accb[8] = {};
    const int arow = (wave * 16 + lr) * SA;
#pragma unroll
    for (int ks = 0; ks < 128; ks += 32) {
        bf16x8 a = *(const bf16x8*)(sm + arow + ks + kq * 8);
#pragma unroll
        for (int nt = 0; nt < 8; ++nt) {
            bf16x8 ba = *(const bf16x8*)(W1aT + (nt * 16 + lr) * 128 + ks + kq * 8);
            acca[nt] = __builtin_amdgcn_mfma_f32_16x16x32_bf16(a, ba, acca[nt], 0, 0, 0);
            bf16x8 bb = *(const bf16x8*)(W1bT + (nt * 16 + lr) * 128 + ks + kq * 8);
            accb[nt] = __builtin_amdgcn_mfma_f32_16x16x32_bf16(a, bb, accb[nt], 0, 0, 0);
        }
    }
    __syncthreads();

    const int node = n0 + mrow;
#pragma unroll
    for (int nt = 0; nt < 8; ++nt) {
        const int col = nt * 16 + lr;
#pragma unroll
        for (int r = 0; r < 4; ++r)
            sm[(wave * 16 + kq * 4 + r) * SA + col] = f2bf(acca[nt][r]);
    }
    __syncthreads();
    if (node < N_NODES) {
        uint4* dst = (uint4*)(P + (size_t)node * HDIM + q * 32);
        const uint4* srcp = (const uint4*)(sm + mrow * SA + q * 32);
#pragma unroll
        for (int j = 0; j < 4; ++j) dst[j] = srcp[j];
    }
    __syncthreads();
#pragma unroll
    for (int nt = 0; nt < 8; ++nt) {
        const int col = nt * 16 + lr;
#pragma unroll
        for (int r = 0; r < 4; ++r)
            sm[(wave * 16 + kq * 4 + r) * SA + col] = f2bf(accb[nt][r]);
    }
    __syncthreads();
    if (node < N_NODES) {
        uint4* dst = (uint4*)(Qm + (size_t)node * HDIM + q * 32);
        const uint4* srcp = (const uint4*)(sm + mrow * SA + q * 32);
#pragma unroll
        for (int j = 0; j < 4; ++j) dst[j] = srcp[j];
    }
}

// ================= edge kernel helpers (32x32 MFMA path) =================

// build A-fragments from gathered P/Q/Lb rows + fd * (bf16 weights from LDS)
static __device__ __forceinline__ void build_afrag(
    const uint4* pu, const uint4* qu, const uint4* lu,
    float f0, float f1, float f2,
    const unsigned int* wlds, int hi, bf16x8* afrag) {
#pragma unroll
    for (int kk = 0; kk < 8; ++kk) {
        const unsigned int* wl = wlds + (kk * 2 + hi) * 12;
        const uint4 w0v = *(const uint4*)(wl);
        const uint4 w1v = *(const uint4*)(wl + 4);
        const uint4 w2v = *(const uint4*)(wl + 8);
        const unsigned int* pw = (const unsigned int*)&pu[kk];
        const unsigned int* qw = (const unsigned int*)&qu[kk];
        const unsigned int* lw = (const unsigned int*)&lu[kk];
        const unsigned int* w0w = (const unsigned int*)&w0v;
        const unsigned int* w1w = (const unsigned int*)&w1v;
        const unsigned int* w2w = (const unsigned int*)&w2v;
        unsigned int ow[4];
#pragma unroll
        for (int w = 0; w < 4; ++w) {
            float x0 = bflo(pw[w]) + bflo(qw[w]) + bflo(lw[w])
                     + f0 * bflo(w0w[w]) + f1 * bflo(w1w[w]) + f2 * bflo(w2w[w]);
            float x1 = bfhi(pw[w]) + bfhi(qw[w]) + bfhi(lw[w])
                     + f0 * bfhi(w0w[w]) + f1 * bfhi(w1w[w]) + f2 * bfhi(w2w[w]);
            ow[w] = cvt_pk_bf16(silu_f(x0), silu_f(x1));
        }
        afrag[kk] = *(bf16x8*)ow;
    }
}

// NOTE: no s_setprio here — R7 measured it pins the schedule and causes a
// mild scratch spill (+43MB TCC traffic, +25us). Plain cluster is fastest.
static __device__ __forceinline__ void do_mfma(
    const bf16x8* afrag, const unsigned short* __restrict__ W2t,
    int row, int hi, f32x16* acc) {
#pragma unroll
    for (int kk = 0; kk < 8; ++kk) {
#pragma unroll
        for (int t4 = 0; t4 < 4; ++t4) {
            bf16x8 bb = *(const bf16x8*)(W2t + (t4 * 32 + row) * 128 + kk * 16 + hi * 8);
            acc[t4] = __builtin_amdgcn_mfma_f32_32x32x16_bf16(afrag[kk], bb, acc[t4], 0, 0, 0);
        }
    }
}

// segmented reduction over 32 sorted rows on the 32x32 C layout
// (row = (reg&3) + 8*(reg>>2) + 4*hi); hi-halves merged via shfl_xor.
// seg[a,b] emitted as +prefix[b] to src[b], -prefix[a-1] to src[a]
static __device__ __forceinline__ void epilogue(
    const f32x16* acc, const int* sc, const int* snq,
    int row, int hi, const float* __restrict__ b2, float* __restrict__ agg) {
#pragma unroll
    for (int t4 = 0; t4 < 4; ++t4) {
        const int col = t4 * 32 + row;
        const float bias = b2[col];
        float p[16], tq[4], to[4];
#pragma unroll
        for (int rq = 0; rq < 4; ++rq) {
            float s0 = silu_f(acc[t4][4 * rq + 0] + bias);
            float s1 = silu_f(acc[t4][4 * rq + 1] + bias);
            float s2 = silu_f(acc[t4][4 * rq + 2] + bias);
            float s3 = silu_f(acc[t4][4 * rq + 3] + bias);
            p[4 * rq + 0] = s0;
            p[4 * rq + 1] = s0 + s1;
            p[4 * rq + 2] = p[4 * rq + 1] + s2;
            p[4 * rq + 3] = p[4 * rq + 2] + s3;
            tq[rq] = p[4 * rq + 3];
            to[rq] = __shfl_xor(tq[rq], 32);
        }
        float cum = 0.f;
#pragma unroll
        for (int rq = 0; rq < 4; ++rq) {
            const float off = cum + (hi ? to[rq] : 0.f);
            cum += tq[rq] + to[rq];
#pragma unroll
            for (int i = 0; i < 4; ++i) {
                const int r = 4 * rq + i;
                const float val = p[r] + off;
                const int myrow = 4 * (2 * rq + hi) + i;
                const bool lastg = (myrow == 31);
                const int nxt = (i < 3) ? sc[r + 1] : snq[rq];
                const bool bnd = lastg || (sc[r] != nxt);
                if (bnd) {
                    atomicAdd(&agg[(size_t)sc[r] * HDIM + col], val);
                    if (!lastg) atomicAdd(&agg[(size_t)nxt * HDIM + col], -val);
                }
            }
        }
    }
}

// ---- edge kernel: 64 edges/wave = two straight-line 32-edge chunks.
// R12 register-economics experiment: chunk-B's Lb gather (32 regs) moves
// from the up-front batch to AFTER chunk-A's MFMA (hidden under A's
// epilogue, pinned by an opaque asm so LICM can't hoist it back). Lb is
// 512KB, L2-hot (edges sharing src share graph), so late L2-hit loads are
// cheap. If arch VGPR drops <=106 (total <=170 with 64 AGPR), HW runs
// 3 waves/SIMD automatically — launch_bounds(256,2) is a floor, not a cap.
#define EDGE_NWG (N_EDGES / 256)   // 3125 blocks of 4 waves x 64 edges
template <bool PACKED>
static __device__ __forceinline__ void fetch_meta(
    int i, const uint4* __restrict__ rec, const int* __restrict__ eidx,
    const int* __restrict__ e2g, const float* __restrict__ frac_diff,
    const unsigned short* __restrict__ perm_lo, const unsigned char* __restrict__ perm_hi,
    int& src, int& dst, int& g, float& f0, float& f1, float& f2) {
    if (PACKED) {
        const uint4 rv = rec[i];
        src = rv.x & 0xFFFF;
        dst = rv.x >> 16;
        g = rv.y & 0xFFFF;
        f0 = bfhi(rv.y);
        f1 = bflo(rv.z);
        f2 = bfhi(rv.z);
    } else {
        const int e = (int)perm_lo[i] | ((int)perm_hi[i] << 16);
        src = eidx[e];
        dst = eidx[N_EDGES + e];
        g = e2g[e];
        f0 = frac_diff[3 * e];
        f1 = frac_diff[3 * e + 1];
        f2 = frac_diff[3 * e + 2];
    }
}

static __device__ __forceinline__ void gather_pq(
    const unsigned short* __restrict__ P, const unsigned short* __restrict__ Qm,
    int src, int dst, int hi, uint4* pu, uint4* qu) {
    const size_t pr = (size_t)src * HDIM, qr = (size_t)dst * HDIM;
#pragma unroll
    for (int kk = 0; kk < 8; ++kk) {
        const int c0 = kk * 16 + hi * 8;
        pu[kk] = *(const uint4*)(P + pr + c0);
        qu[kk] = *(const uint4*)(Qm + qr + c0);
    }
}

static __device__ __forceinline__ void gather_l(
    const unsigned short* __restrict__ Lb, int g, int hi, uint4* lu) {
    const size_t lr = (size_t)g * HDIM;
#pragma unroll
    for (int kk = 0; kk < 8; ++kk) {
        const int c0 = kk * 16 + hi * 8;
        lu[kk] = *(const uint4*)(Lb + lr + c0);
    }
}

static __device__ __forceinline__ void make_sc(int src, int hi, int* sc, int* snq) {
#pragma unroll
    for (int r = 0; r < 16; ++r) sc[r] = __shfl(src, (r & 3) + 8 * (r >> 2) + 4 * hi);
#pragma unroll
    for (int j = 0; j < 4; ++j) snq[j] = __shfl(src, (4 * (2 * j + hi) + 4) & 31);
}

template <bool PACKED>
__global__ __launch_bounds__(256, 2) void edge_kernel(
    const unsigned short* __restrict__ P, const unsigned short* __restrict__ Qm,
    const unsigned short* __restrict__ Lb, const float* __restrict__ frac_diff,
    const int* __restrict__ eidx, const int* __restrict__ e2g,
    const unsigned short* __restrict__ perm_lo, const unsigned char* __restrict__ perm_hi,
    const uint4* __restrict__ rec,
    const float* __restrict__ e_w1, const unsigned short* __restrict__ W2t,
    const float* __restrict__ b2, float* __restrict__ agg) {
    // fd-weight columns of e_w1 (rows 262..264) as bf16 pairs in LDS:
    // layout [kk][hi][rw][4 dwords]; reads are 2-address broadcasts (free).
    __shared__ __align__(16) unsigned int wlds[192];
    const int tid = threadIdx.x;
    {
        const float* wrbase = e_w1 + 262 * HDIM;
        if (tid < 192) {
            const int w = tid & 3, rw = (tid >> 2) % 3, hi = (tid / 12) & 1, kk = tid / 24;
            const int c = kk * 16 + hi * 8 + 2 * w;
            wlds[((kk * 2 + hi) * 3 + rw) * 4 + w] =
                (unsigned int)f2bf(wrbase[rw * HDIM + c]) |
                ((unsigned int)f2bf(wrbase[rw * HDIM + c + 1]) << 16);
        }
    }
    __syncthreads();

    const int wv = tid >> 6, lane = tid & 63;
    const int row = lane & 31, hi = lane >> 5;
    const int base = (blockIdx.x * 4 + wv) * 64;   // this wave's 64 edges

    // ---- metadata for both chunks ----
    int srcA, dstA, gA; float fA0, fA1, fA2;
    fetch_meta<PACKED>(base + row, rec, eidx, e2g, frac_diff, perm_lo, perm_hi,
                       srcA, dstA, gA, fA0, fA1, fA2);
    int srcB, dstB, gB; float fB0, fB1, fB2;
    fetch_meta<PACKED>(base + 32 + row, rec, eidx, e2g, frac_diff, perm_lo, perm_hi,
                       srcB, dstB, gB, fB0, fB1, fB2);

    // ---- up-front gathers: full chunk-A + chunk-B's P/Q only.
    // luB is deferred to after A's MFMA (saves 32 live regs in the A-phase).
    uint4 puA[8], quA[8], luA[8];
    gather_pq(P, Qm, srcA, dstA, hi, puA, quA);
    gather_l(Lb, gA, hi, luA);
    uint4 puB[8], quB[8];
    gather_pq(P, Qm, srcB, dstB, hi, puB, quB);

    // ---- chunk A: afrag -> MFMA -> [issue luB] -> epilogue ----
    uint4 luB[8];
    {
        bf16x8 afrag[8];
        build_afrag(puA, quA, luA, fA0, fA1, fA2, wlds, hi, afrag);
        int sc[16], snq[4];
        make_sc(srcA, hi, sc, snq);
        f32x16 acc[4] = {};
        do_mfma(afrag, W2t, row, hi, acc);
        // issue chunk-B's Lb gather here: L2-hit latency hides under the
        // ~150-inst epilogue. Opaque pin stops LICM from hoisting it up.
        int gB_pin = gB;
        asm volatile("" : "+v"(gB_pin));
        gather_l(Lb, gB_pin, hi, luB);
        epilogue(acc, sc, snq, row, hi, b2, agg);
    }

    // ---- chunk B: afrag -> MFMA -> epilogue ----
    {
        bf16x8 afrag[8];
        build_afrag(puB, quB, luB, fB0, fB1, fB2, wlds, hi, afrag);
        int sc[16], snq[4];
        make_sc(srcB, hi, sc, snq);
        f32x16 acc[4] = {};
        do_mfma(afrag, W2t, row, hi, acc);
        epilogue(acc, sc, snq, row, hi, b2, agg);
    }
}

// ---- node MLP: h = concat(nf, agg/cnt) -> silu -> silu -> + nf (agg aliases out) ----
__global__ __launch_bounds__(256, 4) void node_kernel(
    const float* __restrict__ nf, const float* __restrict__ agg,
    const int* __restrict__ buf,
    const unsigned short* __restrict__ N1t, const float* __restrict__ b1,
    const unsigned short* __restrict__ N2t, const float* __restrict__ b2,
    float* __restrict__ out) {
    constexpr int SA = 264;
    constexpr int S2 = 136;
    constexpr int SFo = 132;
    __shared__ unsigned short sm[64 * SA];
    float* smf = (float*)sm;

    const int tid = threadIdx.x;
    const int n0 = blockIdx.x * 64;
    const int mrow = tid >> 2, q = tid & 3;
    {
        const int node = n0 + mrow;
        unsigned short* row = sm + mrow * SA;
        const int cbq = q * 32;
        if (node < N_NODES) {
            const int c = buf[node] - (node ? buf[node - 1] : 0);
            const float inv = 1.0f / (float)max(c, 1);
            const float4* a4 = (const float4*)(nf + (size_t)node * HDIM) + q * 8;
            const float4* g4 = (const float4*)(agg + (size_t)node * HDIM) + q * 8;
#pragma unroll
            for (int j = 0; j < 8; ++j) {
                float4 v = a4[j];
                *(ushort4*)(row + cbq + 4 * j) =
                    make_ushort4(f2bf(v.x), f2bf(v.y), f2bf(v.z), f2bf(v.w));
                float4 g = g4[j];
                *(ushort4*)(row + HDIM + cbq + 4 * j) =
                    make_ushort4(f2bf(g.x * inv), f2bf(g.y * inv), f2bf(g.z * inv), f2bf(g.w * inv));
            }
        } else {
#pragma unroll
            for (int j = 0; j < 8; ++j) {
                *(ushort4*)(row + cbq + 4 * j) = make_ushort4(0, 0, 0, 0);
                *(ushort4*)(row + HDIM + cbq + 4 * j) = make_ushort4(0, 0, 0, 0);
            }
        }
    }
    __syncthreads();

    const int wave = tid >> 6, lane = tid & 63;
    const int lr = lane & 15, kq = lane >> 4;

    f32x4 acc[8] = {};
    const int arow = (wave * 16 + lr) * SA;
#pragma unroll
    for (int ks = 0; ks < 256; ks += 32) {
        bf16x8 a = *(const bf16x8*)(sm + arow + ks + kq * 8);
#pragma unroll
        for (int nt = 0; nt < 8; ++nt) {
            bf16x8 bb = *(const bf16x8*)(N1t + (nt * 16 + lr) * 256 + ks + kq * 8);
            acc[nt] = __builtin_amdgcn_mfma_f32_16x16x32_bf16(a, bb, acc[nt], 0, 0, 0);
        }
    }
    __syncthreads();

#pragma unroll
    for (int nt = 0; nt < 8; ++nt) {
        const int col = nt * 16 + lr;
        const float bias = b1[col];
#pragma unroll
        for (int r = 0; r < 4; ++r) {
            const int mm = wave * 16 + kq * 4 + r;
            sm[mm * S2 + col] = f2bf(silu_f(acc[nt][r] + bias));
        }
    }
    __syncthreads();

    f32x4 acc2[8] = {};
    const int arow2 = (wave * 16 + lr) * S2;
#pragma unroll
    for (int ks = 0; ks < 128; ks += 32) {
        bf16x8 a = *(const bf16x8*)(sm + arow2 + ks + kq * 8);
#pragma unroll
        for (int nt = 0; nt < 8; ++nt) {
            bf16x8 bb = *(const bf16x8*)(N2t + (nt * 16 + lr) * 128 + ks + kq * 8);
            acc2[nt] = __builtin_amdgcn_mfma_f32_16x16x32_bf16(a, bb, acc2[nt], 0, 0, 0);
        }
    }
    __syncthreads();

#pragma unroll
    for (int nt = 0; nt < 8; ++nt) {
        const int col = nt * 16 + lr;
        const float bias = b2[col];
#pragma unroll
        for (int r = 0; r < 4; ++r) {
            const int mm = wave * 16 + kq * 4 + r;
            smf[mm * SFo + col] = silu_f(acc2[nt][r] + bias);
        }
    }
    __syncthreads();
    {
        const int node = n0 + mrow;
        if (node < N_NODES) {
            const float4* nfr = (const float4*)(nf + (size_t)node * HDIM) + q * 8;
            float4* outr = (float4*)(out + (size_t)node * HDIM) + q * 8;
            const float* st = smf + mrow * SFo + q * 32;
#pragma unroll
            for (int j = 0; j < 8; ++j) {
                float4 v = nfr[j];
                float4 s4 = *(const float4*)(st + 4 * j);
                v.x += s4.x; v.y += s4.y; v.z += s4.z; v.w += s4.w;
                outr[j] = v;
            }
        }
    }
}

extern "C" void kernel_launch(void* const* d_in, const int* in_sizes, int n_in,
                              void* d_out, int out_size, void* d_ws, size_t ws_size,
                              hipStream_t stream) {
    const float* node_features = (const float*)d_in[0];
    const float* lattices = (const float*)d_in[2];
    const float* frac_diff = (const float*)d_in[3];
    const int* edge_index = (const int*)d_in[4];
    const int* edge2graph = (const int*)d_in[5];
    const float* e_w1 = (const float*)d_in[6];
    const float* e_b1 = (const float*)d_in[7];
    const float* e_w2 = (const float*)d_in[8];
    const float* e_b2 = (const float*)d_in[9];
    const float* n_w1 = (const float*)d_in[10];
    const float* n_b1 = (const float*)d_in[11];
    const float* n_w2 = (const float*)d_in[12];
    const float* n_b2 = (const float*)d_in[13];

    // workspace layout (bytes):
    //   0         W1aT | 32768 W1bT | 65536 W2t | 98304 N1t | 163840 N2t
    //   196608    Lb   (G*128 bf16)
    //   720896    P    (N*128 bf16, 12.8MB)
    //   13520896  Q    (N*128 bf16, 12.8MB)
    //   26320896  buf  (N int)
    //   26520896  perm_lo (E u16) | 28120896 perm_hi (E u8)   [fallback path]
    //   28920896  rec  (E x 16B packed sorted metadata)       [packed path, if ws fits]
    // agg lives in d_out (node_kernel reads its own rows before overwriting).
    char* ws = (char*)d_ws;
    unsigned short* W1aT = (unsigned short*)(ws);
    unsigned short* W1bT = (unsigned short*)(ws + 32768);
    unsigned short* W2t  = (unsigned short*)(ws + 65536);
    unsigned short* N1t  = (unsigned short*)(ws + 98304);
    unsigned short* N2t  = (unsigned short*)(ws + 163840);
    unsigned short* Lb   = (unsigned short*)(ws + 196608);
    unsigned short* P    = (unsigned short*)(ws + 720896);
    unsigned short* Qm   = (unsigned short*)(ws + 13520896);
    int* buf             = (int*)(ws + 26320896);
    unsigned short* perm_lo = (unsigned short*)(ws + 26520896);
    unsigned char* perm_hi  = (unsigned char*)(ws + 28120896);
    uint4* rec           = (uint4*)(ws + 28920896);
    float* agg = (float*)d_out;

    // ws_size is fixed for the session -> this branch is deterministic (graph-safe)
    const int packed = (ws_size >= 28920896 + (size_t)N_EDGES * 16) ? 1 : 0;

    hipMemsetAsync(buf, 0, (size_t)N_NODES * 4, stream);

    prep_hist_kernel<<<PREP_BLOCKS + HIST_BLOCKS + ZERO_BLOCKS, 256, 0, stream>>>(
        e_w1, e_w2, n_w1, n_w2, e_b1, lattices, edge_index,
        W1aT, W1bT, W2t, N1t, N2t, Lb, buf, agg);

    scan_kernel<<<1, 1024, 0, stream>>>(buf);

    perm_pq_kernel<<<PERM_BLOCKS2 + PQ_BLOCKS, 256, 0, stream>>>(
        edge_index, edge2graph, frac_diff, buf, perm_lo, perm_hi, rec, packed,
        node_features, W1aT, W1bT, P, Qm);

    if (packed) {
        edge_kernel<true><<<EDGE_NWG, 256, 0, stream>>>(
            P, Qm, Lb, frac_diff, edge_index, edge2graph, perm_lo, perm_hi, rec,
            e_w1, W2t, e_b2, agg);
    } else {
        edge_kernel<false><<<EDGE_NWG, 256, 0, stream>>>(
            P, Qm, Lb, frac_diff, edge_index, edge2graph, perm_lo, perm_hi, rec,
            e_w1, W2t, e_b2, agg);
    }

    node_kernel<<<(N_NODES + 63) / 64, 256, 0, stream>>>(
        node_features, agg, buf, N1t, n_b1, N2t, n_b2, (float*)d_out);
}

// Round 13
// 484.375 us; speedup vs baseline: 1.1604x; 1.0369x over previous
//
#include <hip/hip_runtime.h>

#define N_NODES 50000
#define N_EDGES 800000
#define HDIM 128
#define N_GRAPH 2048

typedef __bf16 bf16x8 __attribute__((ext_vector_type(8)));
typedef float f32x4 __attribute__((ext_vector_type(4)));
typedef float f32x16 __attribute__((ext_vector_type(16)));

// round-to-nearest-even fp32 -> bf16
static __device__ __forceinline__ unsigned short f2bf(float f) {
    unsigned int u = __float_as_uint(f);
    u += 0x7fffu + ((u >> 16) & 1u);
    return (unsigned short)(u >> 16);
}
static __device__ __forceinline__ float bflo(unsigned int u) { return __uint_as_float(u << 16); }
static __device__ __forceinline__ float bfhi(unsigned int u) { return __uint_as_float(u & 0xFFFF0000u); }

// one-instruction RNE pair conversion (same rounding as f2bf), replaces ~9 inst
static __device__ __forceinline__ unsigned int cvt_pk_bf16(float lo, float hi) {
    unsigned int r;
    asm("v_cvt_pk_bf16_f32 %0, %1, %2" : "=v"(r) : "v"(lo), "v"(hi));
    return r;
}

// fast silu: x * rcp(1 + 2^(-x*log2e)) -> v_exp_f32 + v_rcp_f32, ~5 inst
static __device__ __forceinline__ float silu_f(float x) {
    float e = __builtin_amdgcn_exp2f(x * -1.44269504f);
    return x * __builtin_amdgcn_rcpf(1.0f + e);
}

// ---- fused one-shot prep (blocks < 1408) + src histogram + agg zero ----
#define PREP_BLOCKS 1408
#define HIST_BLOCKS 3125
#define ZERO_BLOCKS 6250   // N*HDIM*4B / (256*16B) = 6250 exact
__global__ void prep_hist_kernel(const float* __restrict__ ew1, const float* __restrict__ ew2,
                                 const float* __restrict__ nw1, const float* __restrict__ nw2,
                                 const float* __restrict__ eb1, const float* __restrict__ lattices,
                                 const int* __restrict__ eidx,
                                 unsigned short* __restrict__ W1aT, unsigned short* __restrict__ W1bT,
                                 unsigned short* __restrict__ W2t, unsigned short* __restrict__ N1t,
                                 unsigned short* __restrict__ N2t, unsigned short* __restrict__ Lb,
                                 int* __restrict__ buf, float* __restrict__ agg) {
    const int bid = blockIdx.x;
    if (bid >= PREP_BLOCKS + HIST_BLOCKS) {
        // zero agg (= d_out) so edge_kernel atomics start from 0
        const int idx = (bid - PREP_BLOCKS - HIST_BLOCKS) * 256 + threadIdx.x;
        ((float4*)agg)[idx] = make_float4(0.f, 0.f, 0.f, 0.f);
        return;
    }
    if (bid >= PREP_BLOCKS) {
        int e = (bid - PREP_BLOCKS) * 256 + threadIdx.x;
        if (e < N_EDGES) atomicAdd(&buf[eidx[e]], 1);
        return;
    }
    int i = bid * 256 + threadIdx.x;
    if (i < 16384) {
        int n = i >> 7, k = i & 127;
        W1aT[i] = f2bf(ew1[k * 128 + n]);
    } else if (i < 32768) {
        int j = i - 16384; int n = j >> 7, k = j & 127;
        W1bT[j] = f2bf(ew1[(128 + k) * 128 + n]);
    } else if (i < 49152) {
        int j = i - 32768; int n = j >> 7, k = j & 127;
        W2t[j] = f2bf(ew2[k * 128 + n]);
    } else if (i < 81920) {
        int j = i - 49152; int n = j >> 8, k = j & 255;
        N1t[j] = f2bf(nw1[k * 128 + n]);
    } else if (i < 98304) {
        int j = i - 81920; int n = j >> 7, k = j & 127;
        N2t[j] = f2bf(nw2[k * 128 + n]);
    } else if (i < 98304 + 262144) {
        int j = i - 98304; int g = j >> 7, c = j & 127;
        float s = eb1[c];
#pragma unroll
        for (int t = 0; t < 6; ++t) s += lattices[g * 6 + t] * ew1[(256 + t) * 128 + c];
        Lb[j] = f2bf(s);
    }
}

// ---- two-level wide scan (replaces the 1-block serial scan; that was the
// only whole-GPU-serial phase, ~15-25us of 255 idle CUs per R8's sensitivity).
// S1: 49 blocks x 1024 do block-local EXCLUSIVE scan + write block totals.
// S2: 49 blocks each wave-reduce the preceding totals and add their offset.
// aux lives in a __device__ global (196B; fully rewritten each run -> graph-
// safe and deterministic; no workspace-layout change).
#define SCAN_BLOCKS ((N_NODES + 1023) / 1024)   // 49
__device__ int scan_aux_g[64];

__global__ __launch_bounds__(1024) void scan1_kernel(int* __restrict__ buf) {
    __shared__ int wpart[16];
    const int t = threadIdx.x;
    const int i = blockIdx.x * 1024 + t;
    const int wave = t >> 6, lane = t & 63;
    int v = (i < N_NODES) ? buf[i] : 0;
    int ps = v;                       // wave-level inclusive scan (no barriers)
#pragma unroll
    for (int off = 1; off < 64; off <<= 1) {
        int u = __shfl_up(ps, off);
        if (lane >= off) ps += u;
    }
    if (lane == 63) wpart[wave] = ps;
    __syncthreads();
    if (t == 0) {
        int r = 0;
#pragma unroll
        for (int k = 0; k < 16; ++k) { int u = wpart[k]; wpart[k] = r; r += u; }
        scan_aux_g[blockIdx.x] = r;   // block total
    }
    __syncthreads();
    if (i < N_NODES) buf[i] = wpart[wave] + (ps - v);   // exclusive prefix
}

__global__ __launch_bounds__(1024) void scan2_kernel(int* __restrict__ buf) {
    const int t = threadIdx.x;
    const int b = blockIdx.x;
    __shared__ int off_s;
    if (t < 64) {
        int v = (t < b) ? scan_aux_g[t] : 0;   // totals of preceding blocks
#pragma unroll
        for (int o = 32; o > 0; o >>= 1) v += __shfl_down(v, o);
        if (t == 0) off_s = v;
    }
    __syncthreads();
    const int i = b * 1024 + t;
    if (b > 0 && i < N_NODES) buf[i] += off_s;
}

// ---- fused perm scatter (blocks < 3125) + pq precompute (blocks >= 3125) ----
#define PERM_BLOCKS2 3125
#define PQ_BLOCKS ((N_NODES + 63) / 64)
__global__ __launch_bounds__(256, 4) void perm_pq_kernel(
    const int* __restrict__ eidx, const int* __restrict__ e2g,
    const float* __restrict__ frac_diff, int* __restrict__ buf,
    unsigned short* __restrict__ perm_lo, unsigned char* __restrict__ perm_hi,
    uint4* __restrict__ rec, const int packed,
    const float* __restrict__ nf, const unsigned short* __restrict__ W1aT,
    const unsigned short* __restrict__ W1bT,
    unsigned short* __restrict__ P, unsigned short* __restrict__ Qm) {
    constexpr int SA = 136;
    __shared__ unsigned short sm[64 * SA];
    const int bid = blockIdx.x;
    const int tid = threadIdx.x;

    if (bid < PERM_BLOCKS2) {
        int e = bid * 256 + tid;
        if (e < N_EDGES) {
            int s = eidx[e];
            int pos = atomicAdd(&buf[s], 1);
            if (packed) {
                int d = eidx[N_EDGES + e];
                int g = e2g[e];
                unsigned int w0 = (unsigned int)s | ((unsigned int)d << 16);
                unsigned int w1 = (unsigned int)g | ((unsigned int)f2bf(frac_diff[3 * e]) << 16);
                unsigned int w2 = (unsigned int)f2bf(frac_diff[3 * e + 1]) |
                                  ((unsigned int)f2bf(frac_diff[3 * e + 2]) << 16);
                rec[pos] = make_uint4(w0, w1, w2, 0u);
            } else {
                perm_lo[pos] = (unsigned short)(e & 0xFFFF);
                perm_hi[pos] = (unsigned char)(e >> 16);
            }
        }
        return;
    }

    const int n0 = (bid - PERM_BLOCKS2) * 64;
    const int mrow = tid >> 2, q = tid & 3;
    {
        const int node = n0 + mrow;
        unsigned short* row = sm + mrow * SA + q * 32;
        if (node < N_NODES) {
            const float4* a4 = (const float4*)(nf + (size_t)node * HDIM) + q * 8;
#pragma unroll
            for (int j = 0; j < 8; ++j) {
                float4 v = a4[j];
                *(ushort4*)(row + 4 * j) = make_ushort4(f2bf(v.x), f2bf(v.y), f2bf(v.z), f2bf(v.w));
            }
        } else {
#pragma unroll
            for (int j = 0; j < 8; ++j) *(ushort4*)(row + 4 * j) = make_ushort4(0, 0, 0, 0);
        }
    }
    __syncthreads();

    const int wave = tid >> 6, lane = tid & 63;
    const int lr = lane & 15, kq = lane >> 4;
    f32x4 acca[8] = {}, accb[8] = {};
    const int arow = (wave * 16 + lr) * SA;
#pragma unroll
    for (int ks = 0; ks < 128; ks += 32) {
        bf16x8 a = *(const bf16x8*)(sm + arow + ks + kq * 8);
#pragma unroll
        for (int nt = 0; nt < 8; ++nt) {
            bf16x8 ba = *(const bf16x8*)(W1aT + (nt * 16 + lr) * 128 + ks + kq * 8);
            acca[nt] = __builtin_amdgcn_mfma_f32_16x16x32_bf16(a, ba, acca[nt], 0, 0, 0);
            bf16x8 bb = *(const bf16x8*)(W1bT + (nt * 16 + lr) * 128 + ks + kq * 8);
            accb[nt] = __builtin_amdgcn_mfma_f32_16x16x32_bf16(a, bb, accb[nt], 0, 0, 0);
        }
    }
    __syncthreads();

    const int node = n0 + mrow;
#pragma unroll
    for (int nt = 0; nt < 8; ++nt) {
        const int col = nt * 16 + lr;
#pragma unroll
        for (int r = 0; r < 4; ++r)
            sm[(wave * 16 + kq * 4 + r) * SA + col] = f2bf(acca[nt][r]);
    }
    __syncthreads();
    if (node < N_NODES) {
        uint4* dst = (uint4*)(P + (size_t)node * HDIM + q * 32);
        const uint4* srcp = (const uint4*)(sm + mrow * SA + q * 32);
#pragma unroll
        for (int j = 0; j < 4; ++j) dst[j] = srcp[j];
    }
    __syncthreads();
#pragma unroll
    for (int nt = 0; nt < 8; ++nt) {
        const int col = nt * 16 + lr;
#pragma unroll
        for (int r = 0; r < 4; ++r)
            sm[(wave * 16 + kq * 4 + r) * SA + col] = f2bf(accb[nt][r]);
    }
    __syncthreads();
    if (node < N_NODES) {
        uint4* dst = (uint4*)(Qm + (size_t)node * HDIM + q * 32);
        const uint4* srcp = (const uint4*)(sm + mrow * SA + q * 32);
#pragma unroll
        for (int j = 0; j < 4; ++j) dst[j] = srcp[j];
    }
}

// ================= edge kernel helpers (32x32 MFMA path) =================

// build A-fragments from gathered P/Q/Lb rows + fd * (bf16 weights from LDS)
static __device__ __forceinline__ void build_afrag(
    const uint4* pu, const uint4* qu, const uint4* lu,
    float f0, float f1, float f2,
    const unsigned int* wlds, int hi, bf16x8* afrag) {
#pragma unroll
    for (int kk = 0; kk < 8; ++kk) {
        const unsigned int* wl = wlds + (kk * 2 + hi) * 12;
        const uint4 w0v = *(const uint4*)(wl);
        const uint4 w1v = *(const uint4*)(wl + 4);
        const uint4 w2v = *(const uint4*)(wl + 8);
        const unsigned int* pw = (const unsigned int*)&pu[kk];
        const unsigned int* qw = (const unsigned int*)&qu[kk];
        const unsigned int* lw = (const unsigned int*)&lu[kk];
        const unsigned int* w0w = (const unsigned int*)&w0v;
        const unsigned int* w1w = (const unsigned int*)&w1v;
        const unsigned int* w2w = (const unsigned int*)&w2v;
        unsigned int ow[4];
#pragma unroll
        for (int w = 0; w < 4; ++w) {
            float x0 = bflo(pw[w]) + bflo(qw[w]) + bflo(lw[w])
                     + f0 * bflo(w0w[w]) + f1 * bflo(w1w[w]) + f2 * bflo(w2w[w]);
            float x1 = bfhi(pw[w]) + bfhi(qw[w]) + bfhi(lw[w])
                     + f0 * bfhi(w0w[w]) + f1 * bfhi(w1w[w]) + f2 * bfhi(w2w[w]);
            ow[w] = cvt_pk_bf16(silu_f(x0), silu_f(x1));
        }
        afrag[kk] = *(bf16x8*)ow;
    }
}

// NOTE: no s_setprio here — R7 measured it pins the schedule and causes a
// mild scratch spill (+43MB TCC traffic, +25us). Plain cluster is fastest.
static __device__ __forceinline__ void do_mfma(
    const bf16x8* afrag, const unsigned short* __restrict__ W2t,
    int row, int hi, f32x16* acc) {
#pragma unroll
    for (int kk = 0; kk < 8; ++kk) {
#pragma unroll
        for (int t4 = 0; t4 < 4; ++t4) {
            bf16x8 bb = *(const bf16x8*)(W2t + (t4 * 32 + row) * 128 + kk * 16 + hi * 8);
            acc[t4] = __builtin_amdgcn_mfma_f32_32x32x16_bf16(afrag[kk], bb, acc[t4], 0, 0, 0);
        }
    }
}

// segmented reduction over 32 sorted rows on the 32x32 C layout
// (row = (reg&3) + 8*(reg>>2) + 4*hi); hi-halves merged via shfl_xor.
// seg[a,b] emitted as +prefix[b] to src[b], -prefix[a-1] to src[a]
static __device__ __forceinline__ void epilogue(
    const f32x16* acc, const int* sc, const int* snq,
    int row, int hi, const float* __restrict__ b2, float* __restrict__ agg) {
#pragma unroll
    for (int t4 = 0; t4 < 4; ++t4) {
        const int col = t4 * 32 + row;
        const float bias = b2[col];
        float p[16], tq[4], to[4];
#pragma unroll
        for (int rq = 0; rq < 4; ++rq) {
            float s0 = silu_f(acc[t4][4 * rq + 0] + bias);
            float s1 = silu_f(acc[t4][4 * rq + 1] + bias);
            float s2 = silu_f(acc[t4][4 * rq + 2] + bias);
            float s3 = silu_f(acc[t4][4 * rq + 3] + bias);
            p[4 * rq + 0] = s0;
            p[4 * rq + 1] = s0 + s1;
            p[4 * rq + 2] = p[4 * rq + 1] + s2;
            p[4 * rq + 3] = p[4 * rq + 2] + s3;
            tq[rq] = p[4 * rq + 3];
            to[rq] = __shfl_xor(tq[rq], 32);
        }
        float cum = 0.f;
#pragma unroll
        for (int rq = 0; rq < 4; ++rq) {
            const float off = cum + (hi ? to[rq] : 0.f);
            cum += tq[rq] + to[rq];
#pragma unroll
            for (int i = 0; i < 4; ++i) {
                const int r = 4 * rq + i;
                const float val = p[r] + off;
                const int myrow = 4 * (2 * rq + hi) + i;
                const bool lastg = (myrow == 31);
                const int nxt = (i < 3) ? sc[r + 1] : snq[rq];
                const bool bnd = lastg || (sc[r] != nxt);
                if (bnd) {
                    atomicAdd(&agg[(size_t)sc[r] * HDIM + col], val);
                    if (!lastg) atomicAdd(&agg[(size_t)nxt * HDIM + col], -val);
                }
            }
        }
    }
}

// ---- edge kernel: 64 edges/wave = two straight-line 32-edge chunks.
// R13: ALL of chunk-B's gathers (not just Lb) are issued after chunk-A's
// MFMA, pinned by opaque asm. A's epilogue (~200 VALU inst, ~1600 device
// cycles at 2 waves/SIMD) covers even the ~900cy HBM-miss path for the
// random P/Q gathers, and peak live registers during A-compute drop by 64.
// (R12's luB-only deferral: 210.7 -> 205.4us at unchanged VGPR=128.)
#define EDGE_NWG (N_EDGES / 256)   // 3125 blocks of 4 waves x 64 edges
template <bool PACKED>
static __device__ __forceinline__ void fetch_meta(
    int i, const uint4* __restrict__ rec, const int* __restrict__ eidx,
    const int* __restrict__ e2g, const float* __restrict__ frac_diff,
    const unsigned short* __restrict__ perm_lo, const unsigned char* __restrict__ perm_hi,
    int& src, int& dst, int& g, float& f0, float& f1, float& f2) {
    if (PACKED) {
        const uint4 rv = rec[i];
        src = rv.x & 0xFFFF;
        dst = rv.x >> 16;
        g = rv.y & 0xFFFF;
        f0 = bfhi(rv.y);
        f1 = bflo(rv.z);
        f2 = bfhi(rv.z);
    } else {
        const int e = (int)perm_lo[i] | ((int)perm_hi[i] << 16);
        src = eidx[e];
        dst = eidx[N_EDGES + e];
        g = e2g[e];
        f0 = frac_diff[3 * e];
        f1 = frac_diff[3 * e + 1];
        f2 = frac_diff[3 * e + 2];
    }
}

static __device__ __forceinline__ void gather_pq(
    const unsigned short* __restrict__ P, const unsigned short* __restrict__ Qm,
    int src, int dst, int hi, uint4* pu, uint4* qu) {
    const size_t pr = (size_t)src * HDIM, qr = (size_t)dst * HDIM;
#pragma unroll
    for (int kk = 0; kk < 8; ++kk) {
        const int c0 = kk * 16 + hi * 8;
        pu[kk] = *(const uint4*)(P + pr + c0);
        qu[kk] = *(const uint4*)(Qm + qr + c0);
    }
}

static __device__ __forceinline__ void gather_l(
    const unsigned short* __restrict__ Lb, int g, int hi, uint4* lu) {
    const size_t lr = (size_t)g * HDIM;
#pragma unroll
    for (int kk = 0; kk < 8; ++kk) {
        const int c0 = kk * 16 + hi * 8;
        lu[kk] = *(const uint4*)(Lb + lr + c0);
    }
}

static __device__ __forceinline__ void make_sc(int src, int hi, int* sc, int* snq) {
#pragma unroll
    for (int r = 0; r < 16; ++r) sc[r] = __shfl(src, (r & 3) + 8 * (r >> 2) + 4 * hi);
#pragma unroll
    for (int j = 0; j < 4; ++j) snq[j] = __shfl(src, (4 * (2 * j + hi) + 4) & 31);
}

template <bool PACKED>
__global__ __launch_bounds__(256, 2) void edge_kernel(
    const unsigned short* __restrict__ P, const unsigned short* __restrict__ Qm,
    const unsigned short* __restrict__ Lb, const float* __restrict__ frac_diff,
    const int* __restrict__ eidx, const int* __restrict__ e2g,
    const unsigned short* __restrict__ perm_lo, const unsigned char* __restrict__ perm_hi,
    const uint4* __restrict__ rec,
    const float* __restrict__ e_w1, const unsigned short* __restrict__ W2t,
    const float* __restrict__ b2, float* __restrict__ agg) {
    // fd-weight columns of e_w1 (rows 262..264) as bf16 pairs in LDS:
    // layout [kk][hi][rw][4 dwords]; reads are 2-address broadcasts (free).
    __shared__ __align__(16) unsigned int wlds[192];
    const int tid = threadIdx.x;
    {
        const float* wrbase = e_w1 + 262 * HDIM;
        if (tid < 192) {
            const int w = tid & 3, rw = (tid >> 2) % 3, hi = (tid / 12) & 1, kk = tid / 24;
            const int c = kk * 16 + hi * 8 + 2 * w;
            wlds[((kk * 2 + hi) * 3 + rw) * 4 + w] =
                (unsigned int)f2bf(wrbase[rw * HDIM + c]) |
                ((unsigned int)f2bf(wrbase[rw * HDIM + c + 1]) << 16);
        }
    }
    __syncthreads();

    const int wv = tid >> 6, lane = tid & 63;
    const int row = lane & 31, hi = lane >> 5;
    const int base = (blockIdx.x * 4 + wv) * 64;   // this wave's 64 edges

    // ---- metadata for both chunks ----
    int srcA, dstA, gA; float fA0, fA1, fA2;
    fetch_meta<PACKED>(base + row, rec, eidx, e2g, frac_diff, perm_lo, perm_hi,
                       srcA, dstA, gA, fA0, fA1, fA2);
    int srcB, dstB, gB; float fB0, fB1, fB2;
    fetch_meta<PACKED>(base + 32 + row, rec, eidx, e2g, frac_diff, perm_lo, perm_hi,
                       srcB, dstB, gB, fB0, fB1, fB2);

    // ---- up-front gathers: chunk-A only (chunk-B fully deferred) ----
    uint4 puA[8], quA[8], luA[8];
    gather_pq(P, Qm, srcA, dstA, hi, puA, quA);
    gather_l(Lb, gA, hi, luA);

    // ---- chunk A: afrag -> MFMA -> [issue all B gathers] -> epilogue ----
    uint4 puB[8], quB[8], luB[8];
    {
        bf16x8 afrag[8];
        build_afrag(puA, quA, luA, fA0, fA1, fA2, wlds, hi, afrag);
        int sc[16], snq[4];
        make_sc(srcA, hi, sc, snq);
        f32x16 acc[4] = {};
        do_mfma(afrag, W2t, row, hi, acc);
        // issue chunk-B's gathers here: their latency hides under the
        // ~200-inst epilogue. Opaque pins stop LICM from hoisting them up.
        int sB = srcB, dB = dstB, gB_pin = gB;
        asm volatile("" : "+v"(sB), "+v"(dB), "+v"(gB_pin));
        gather_pq(P, Qm, sB, dB, hi, puB, quB);
        gather_l(Lb, gB_pin, hi, luB);
        epilogue(acc, sc, snq, row, hi, b2, agg);
    }

    // ---- chunk B: afrag -> MFMA -> epilogue ----
    {
        bf16x8 afrag[8];
        build_afrag(puB, quB, luB, fB0, fB1, fB2, wlds, hi, afrag);
        int sc[16], snq[4];
        make_sc(srcB, hi, sc, snq);
        f32x16 acc[4] = {};
        do_mfma(afrag, W2t, row, hi, acc);
        epilogue(acc, sc, snq, row, hi, b2, agg);
    }
}

// ---- node MLP: h = concat(nf, agg/cnt) -> silu -> silu -> + nf (agg aliases out) ----
__global__ __launch_bounds__(256, 4) void node_kernel(
    const float* __restrict__ nf, const float* __restrict__ agg,
    const int* __restrict__ buf,
    const unsigned short* __restrict__ N1t, const float* __restrict__ b1,
    const unsigned short* __restrict__ N2t, const float* __restrict__ b2,
    float* __restrict__ out) {
    constexpr int SA = 264;
    constexpr int S2 = 136;
    constexpr int SFo = 132;
    __shared__ unsigned short sm[64 * SA];
    float* smf = (float*)sm;

    const int tid = threadIdx.x;
    const int n0 = blockIdx.x * 64;
    const int mrow = tid >> 2, q = tid & 3;
    {
        const int node = n0 + mrow;
        unsigned short* row = sm + mrow * SA;
        const int cbq = q * 32;
        if (node < N_NODES) {
            const int c = buf[node] - (node ? buf[node - 1] : 0);
            const float inv = 1.0f / (float)max(c, 1);
            const float4* a4 = (const float4*)(nf + (size_t)node * HDIM) + q * 8;
            const float4* g4 = (const float4*)(agg + (size_t)node * HDIM) + q * 8;
#pragma unroll
            for (int j = 0; j < 8; ++j) {
                float4 v = a4[j];
                *(ushort4*)(row + cbq + 4 * j) =
                    make_ushort4(f2bf(v.x), f2bf(v.y), f2bf(v.z), f2bf(v.w));
                float4 g = g4[j];
                *(ushort4*)(row + HDIM + cbq + 4 * j) =
                    make_ushort4(f2bf(g.x * inv), f2bf(g.y * inv), f2bf(g.z * inv), f2bf(g.w * inv));
            }
        } else {
#pragma unroll
            for (int j = 0; j < 8; ++j) {
                *(ushort4*)(row + cbq + 4 * j) = make_ushort4(0, 0, 0, 0);
                *(ushort4*)(row + HDIM + cbq + 4 * j) = make_ushort4(0, 0, 0, 0);
            }
        }
    }
    __syncthreads();

    const int wave = tid >> 6, lane = tid & 63;
    const int lr = lane & 15, kq = lane >> 4;

    f32x4 acc[8] = {};
    const int arow = (wave * 16 + lr) * SA;
#pragma unroll
    for (int ks = 0; ks < 256; ks += 32) {
        bf16x8 a = *(const bf16x8*)(sm + arow + ks + kq * 8);
#pragma unroll
        for (int nt = 0; nt < 8; ++nt) {
            bf16x8 bb = *(const bf16x8*)(N1t + (nt * 16 + lr) * 256 + ks + kq * 8);
            acc[nt] = __builtin_amdgcn_mfma_f32_16x16x32_bf16(a, bb, acc[nt], 0, 0, 0);
        }
    }
    __syncthreads();

#pragma unroll
    for (int nt = 0; nt < 8; ++nt) {
        const int col = nt * 16 + lr;
        const float bias = b1[col];
#pragma unroll
        for (int r = 0; r < 4; ++r) {
            const int mm = wave * 16 + kq * 4 + r;
            sm[mm * S2 + col] = f2bf(silu_f(acc[nt][r] + bias));
        }
    }
    __syncthreads();

    f32x4 acc2[8] = {};
    const int arow2 = (wave * 16 + lr) * S2;
#pragma unroll
    for (int ks = 0; ks < 128; ks += 32) {
        bf16x8 a = *(const bf16x8*)(sm + arow2 + ks + kq * 8);
#pragma unroll
        for (int nt = 0; nt < 8; ++nt) {
            bf16x8 bb = *(const bf16x8*)(N2t + (nt * 16 + lr) * 128 + ks + kq * 8);
            acc2[nt] = __builtin_amdgcn_mfma_f32_16x16x32_bf16(a, bb, acc2[nt], 0, 0, 0);
        }
    }
    __syncthreads();

#pragma unroll
    for (int nt = 0; nt < 8; ++nt) {
        const int col = nt * 16 + lr;
        const float bias = b2[col];
#pragma unroll
        for (int r = 0; r < 4; ++r) {
            const int mm = wave * 16 + kq * 4 + r;
            smf[mm * SFo + col] = silu_f(acc2[nt][r] + bias);
        }
    }
    __syncthreads();
    {
        const int node = n0 + mrow;
        if (node < N_NODES) {
            const float4* nfr = (const float4*)(nf + (size_t)node * HDIM) + q * 8;
            float4* outr = (float4*)(out + (size_t)node * HDIM) + q * 8;
            const float* st = smf + mrow * SFo + q * 32;
#pragma unroll
            for (int j = 0; j < 8; ++j) {
                float4 v = nfr[j];
                float4 s4 = *(const float4*)(st + 4 * j);
                v.x += s4.x; v.y += s4.y; v.z += s4.z; v.w += s4.w;
                outr[j] = v;
            }
        }
    }
}

extern "C" void kernel_launch(void* const* d_in, const int* in_sizes, int n_in,
                              void* d_out, int out_size, void* d_ws, size_t ws_size,
                              hipStream_t stream) {
    const float* node_features = (const float*)d_in[0];
    const float* lattices = (const float*)d_in[2];
    const float* frac_diff = (const float*)d_in[3];
    const int* edge_index = (const int*)d_in[4];
    const int* edge2graph = (const int*)d_in[5];
    const float* e_w1 = (const float*)d_in[6];
    const float* e_b1 = (const float*)d_in[7];
    const float* e_w2 = (const float*)d_in[8];
    const float* e_b2 = (const float*)d_in[9];
    const float* n_w1 = (const float*)d_in[10];
    const float* n_b1 = (const float*)d_in[11];
    const float* n_w2 = (const float*)d_in[12];
    const float* n_b2 = (const float*)d_in[13];

    // workspace layout (bytes):
    //   0         W1aT | 32768 W1bT | 65536 W2t | 98304 N1t | 163840 N2t
    //   196608    Lb   (G*128 bf16)
    //   720896    P    (N*128 bf16, 12.8MB)
    //   13520896  Q    (N*128 bf16, 12.8MB)
    //   26320896  buf  (N int)
    //   26520896  perm_lo (E u16) | 28120896 perm_hi (E u8)   [fallback path]
    //   28920896  rec  (E x 16B packed sorted metadata)       [packed path, if ws fits]
    // agg lives in d_out (node_kernel reads its own rows before overwriting).
    char* ws = (char*)d_ws;
    unsigned short* W1aT = (unsigned short*)(ws);
    unsigned short* W1bT = (unsigned short*)(ws + 32768);
    unsigned short* W2t  = (unsigned short*)(ws + 65536);
    unsigned short* N1t  = (unsigned short*)(ws + 98304);
    unsigned short* N2t  = (unsigned short*)(ws + 163840);
    unsigned short* Lb   = (unsigned short*)(ws + 196608);
    unsigned short* P    = (unsigned short*)(ws + 720896);
    unsigned short* Qm   = (unsigned short*)(ws + 13520896);
    int* buf             = (int*)(ws + 26320896);
    unsigned short* perm_lo = (unsigned short*)(ws + 26520896);
    unsigned char* perm_hi  = (unsigned char*)(ws + 28120896);
    uint4* rec           = (uint4*)(ws + 28920896);
    float* agg = (float*)d_out;

    // ws_size is fixed for the session -> this branch is deterministic (graph-safe)
    const int packed = (ws_size >= 28920896 + (size_t)N_EDGES * 16) ? 1 : 0;

    hipMemsetAsync(buf, 0, (size_t)N_NODES * 4, stream);

    prep_hist_kernel<<<PREP_BLOCKS + HIST_BLOCKS + ZERO_BLOCKS, 256, 0, stream>>>(
        e_w1, e_w2, n_w1, n_w2, e_b1, lattices, edge_index,
        W1aT, W1bT, W2t, N1t, N2t, Lb, buf, agg);

    scan1_kernel<<<SCAN_BLOCKS, 1024, 0, stream>>>(buf);
    scan2_kernel<<<SCAN_BLOCKS, 1024, 0, stream>>>(buf);

    perm_pq_kernel<<<PERM_BLOCKS2 + PQ_BLOCKS, 256, 0, stream>>>(
        edge_index, edge2graph, frac_diff, buf, perm_lo, perm_hi, rec, packed,
        node_features, W1aT, W1bT, P, Qm);

    if (packed) {
        edge_kernel<true><<<EDGE_NWG, 256, 0, stream>>>(
            P, Qm, Lb, frac_diff, edge_index, edge2graph, perm_lo, perm_hi, rec,
            e_w1, W2t, e_b2, agg);
    } else {
        edge_kernel<false><<<EDGE_NWG, 256, 0, stream>>>(
            P, Qm, Lb, frac_diff, edge_index, edge2graph, perm_lo, perm_hi, rec,
            e_w1, W2t, e_b2, agg);
    }

    node_kernel<<<(N_NODES + 63) / 64, 256, 0, stream>>>(
        node_features, agg, buf, N1t, n_b1, N2t, n_b2, (float*)d_out);
}